// Round 5
// baseline (488.108 us; speedup 1.0000x reference)
//
#include <hip/hip_runtime.h>
#include <hip/hip_fp16.h>
#include <math.h>

#define NNODES 50000
#define IND    128
#define NH     8
#define OD     16
#define HD     128          // NH*OD
#define NEDGE  1600000
#define NOUT   272          // 128 K + 128 V + 16 Qsum = 17 n-tiles of 16
#define HB2    6250         // hist blocks (256 edges each)
#define CB     3125         // h->fp16 convert blocks (2048 elems each; 3125*2048 = 6.4M exact)
#define PB2    ((NNODES + 63) / 64)      // 782 MFMA-proj blocks (64 rows each)
#define NB1    ((NNODES + 255) / 256)    // 196 scan blocks

typedef _Float16 half8  __attribute__((ext_vector_type(8)));
typedef float    floatx4 __attribute__((ext_vector_type(4)));

struct h2x2 { __half2 a, b; };           // one 8B packed load: 4 fp16

// ---------------- Fused: dst-histogram + h->fp16 convert + W16/b_all build ----
__global__ __launch_bounds__(256) void conv_hist_kernel(
    const float* __restrict__ hmat,
    const float* __restrict__ Qw, const float* __restrict__ Qb,
    const float* __restrict__ Kw, const float* __restrict__ Kb,
    const float* __restrict__ Vw, const float* __restrict__ Vb,
    const int* __restrict__ dst,
    _Float16* __restrict__ h16, _Float16* __restrict__ W16,
    float* __restrict__ b_all, int* __restrict__ count)
{
    const int bid = blockIdx.x;
    if (bid < HB2) {                                   // histogram
        int e = bid * 256 + threadIdx.x;
        if (e < NEDGE) atomicAdd(&count[dst[e]], 1);
        return;
    }
    if (bid < HB2 + CB) {                              // h -> fp16
        const size_t i = (size_t)(bid - HB2) * 256 + threadIdx.x;  // 8 floats each
        const float4* hp = (const float4*)hmat;
        float4 x = hp[i * 2];
        float4 y = hp[i * 2 + 1];
        half8 o;
        o[0] = (_Float16)x.x; o[1] = (_Float16)x.y;
        o[2] = (_Float16)x.z; o[3] = (_Float16)x.w;
        o[4] = (_Float16)y.x; o[5] = (_Float16)y.y;
        o[6] = (_Float16)y.z; o[7] = (_Float16)y.w;
        *(half8*)(h16 + i * 8) = o;
        return;
    }
    // single block: build W16 = [Kw | Vw | sum_h Qw] fp16 and b_all fp32
    for (int i = threadIdx.x; i < NOUT * IND; i += 256) {
        int r = i >> 7, c = i & 127;
        float v;
        if (r < 128)       v = Kw[i];
        else if (r < 256)  v = Vw[i - 128 * IND];
        else {
            v = 0.f;
#pragma unroll
            for (int hh = 0; hh < NH; hh++) v += Qw[((hh << 4) + (r - 256)) * IND + c];
        }
        W16[i] = (_Float16)v;
    }
    for (int i = threadIdx.x; i < NOUT; i += 256) {
        float v;
        if (i < 128)      v = Kb[i];
        else if (i < 256) v = Vb[i - 128];
        else {
            v = 0.f;
#pragma unroll
            for (int hh = 0; hh < NH; hh++) v += Qb[(hh << 4) + (i - 256)];
        }
        b_all[i] = v;
    }
}

// ---------------- MFMA projection: [50000 x 128] @ [128 x 272] ----------------
// Block = 4 waves; wave = one 16-row M-tile. A-frags (4 k-steps) in regs,
// B-frags streamed from L1/L2-hot W16. No LDS.
// A: lane l holds A[m=l&15][k=(l>>4)*8+j]; C/D: col=l&15, row=(l>>4)*4+reg.
__global__ __launch_bounds__(256) void proj_mfma_kernel(
    const _Float16* __restrict__ h16, const _Float16* __restrict__ W16,
    const float* __restrict__ b_all,
    __half* __restrict__ KVbuf, float* __restrict__ Qs)
{
    const int wave = threadIdx.x >> 6;
    const int l    = threadIdx.x & 63;
    const int cl   = l & 15;
    const int quad = l >> 4;
    const int m0   = blockIdx.x * 64 + wave * 16;      // wave's node base

    const _Float16* ab = h16 + (size_t)(m0 + cl) * IND + quad * 8;
    half8 afrag[4];
#pragma unroll
    for (int ks = 0; ks < 4; ks++) afrag[ks] = *(const half8*)(ab + ks * 32);

    const int rowbase = m0 + quad * 4;

#pragma unroll 4
    for (int t = 0; t < 17; t++) {
        const _Float16* wb = W16 + (size_t)(t * 16 + cl) * IND + quad * 8;
        floatx4 acc = {0.f, 0.f, 0.f, 0.f};
#pragma unroll
        for (int ks = 0; ks < 4; ks++)
            acc = __builtin_amdgcn_mfma_f32_16x16x32_f16(
                afrag[ks], *(const half8*)(wb + ks * 32), acc, 0, 0, 0);

        const float bias = b_all[t * 16 + cl];
        if (t < 16) {
            const int col = t * 16 + cl;
#pragma unroll
            for (int r = 0; r < 4; r++) {
                int node = rowbase + r;
                if (node < NNODES)
                    KVbuf[(size_t)node * 256 + col] = __float2half_rn(acc[r] + bias);
            }
        } else {
#pragma unroll
            for (int r = 0; r < 4; r++) {
                int node = rowbase + r;
                if (node < NNODES)
                    Qs[(size_t)node * OD + cl] = acc[r] + bias;
            }
        }
    }
}

// ---------------- CSR build: scan / scatter -----------------------------------
__global__ __launch_bounds__(256) void scan1_kernel(
    const int* __restrict__ count, int* __restrict__ incl, int* __restrict__ bsum)
{
    __shared__ int sd[256];
    const int i = blockIdx.x * 256 + threadIdx.x;
    sd[threadIdx.x] = (i < NNODES) ? count[i] : 0;
    __syncthreads();
    for (int ofs = 1; ofs < 256; ofs <<= 1) {
        int x = (threadIdx.x >= ofs) ? sd[threadIdx.x - ofs] : 0;
        __syncthreads();
        sd[threadIdx.x] += x;
        __syncthreads();
    }
    if (i < NNODES) incl[i] = sd[threadIdx.x];
    if (threadIdx.x == 255) bsum[blockIdx.x] = sd[255];
}

__global__ __launch_bounds__(256) void scan2_kernel(int* __restrict__ bsum)
{
    __shared__ int sd[256];
    sd[threadIdx.x] = (threadIdx.x < NB1) ? bsum[threadIdx.x] : 0;
    __syncthreads();
    for (int ofs = 1; ofs < 256; ofs <<= 1) {
        int x = (threadIdx.x >= ofs) ? sd[threadIdx.x - ofs] : 0;
        __syncthreads();
        sd[threadIdx.x] += x;
        __syncthreads();
    }
    if (threadIdx.x < NB1) bsum[threadIdx.x] = sd[threadIdx.x];  // inclusive
}

__global__ __launch_bounds__(256) void scan3_kernel(
    const int* __restrict__ count, const int* __restrict__ incl,
    const int* __restrict__ bsum, int* __restrict__ offs, int* __restrict__ cursor)
{
    const int i = blockIdx.x * 256 + threadIdx.x;
    if (i >= NNODES) return;
    int prev = (blockIdx.x > 0) ? bsum[blockIdx.x - 1] : 0;
    int e = incl[i] - count[i] + prev;
    offs[i]   = e;
    cursor[i] = e;
}

__global__ __launch_bounds__(256) void scatter_kernel(
    const int* __restrict__ src, const int* __restrict__ dst,
    int* __restrict__ cursor, int* __restrict__ eidx)
{
    int e = blockIdx.x * 256 + threadIdx.x;
    if (e < NEDGE) {
        int d = dst[e];
        int pos = atomicAdd(&cursor[d], 1);
        eidx[pos] = src[e];
    }
}

// ---------------- Gather-reduce: one wave per destination node ----------------
// Packed fp16 KV row = 512B = 64 h2x2: lane l loads half-elems [4l,4l+3]
// (lanes 0-31 = K, lanes 32-63 = V). Score on K lanes (head l>>2, xor{1,2});
// V lanes grab the score via shfl from K lane (l&28) and keep 4 accumulators.
__global__ __launch_bounds__(256) void gather_kernel(
    const __half* __restrict__ KVbuf, const float* __restrict__ Qs,
    const int* __restrict__ offs, const int* __restrict__ count,
    const int* __restrict__ eidx,
    float* __restrict__ out)
{
    const int n = blockIdx.x * 4 + (threadIdx.x >> 6);
    const int l = threadIdx.x & 63;
    if (n >= NNODES) return;

    const h2x2* KVp = (const h2x2*)KVbuf;          // 64 h2x2 per node row
    const float4 qf = ((const float4*)(Qs + (size_t)n * OD))[l & 3];
    const int srcl = (l & 32) ? (l & 28) : l;       // V lane -> K lane 4*head

    const int off = offs[n];
    const int cnt = count[n];

    float a0 = 0.f, a1 = 0.f, a2 = 0.f, a3 = 0.f, zacc = 0.f;

    // self-loop (s = n)
    {
        h2x2 w = KVp[(size_t)n * 64 + l];
        float2 f0 = __half22float2(w.a);
        float2 f1 = __half22float2(w.b);
        float p = f0.x * qf.x + f0.y * qf.y + f1.x * qf.z + f1.y * qf.w;
        p += __shfl_xor(p, 1, 64);
        p += __shfl_xor(p, 2, 64);
        float sc = __expf(fminf(5.f, fmaxf(-5.f, p * 0.25f)));
        zacc += sc;
        float scv = __shfl(sc, srcl, 64);
        a0 = fmaf(f0.x, scv, a0); a1 = fmaf(f0.y, scv, a1);
        a2 = fmaf(f1.x, scv, a2); a3 = fmaf(f1.y, scv, a3);
    }

    for (int base = 0; base < cnt; base += 64) {
        const int m  = min(64, cnt - base);
        const int id = (base + l < cnt) ? eidx[off + base + l] : 0;

        int s0 = __shfl(id, 0, 64);
        h2x2 w = KVp[(size_t)s0 * 64 + l];

        for (int j = 0; j < m; j++) {
            h2x2 wn = w;
            if (j + 1 < m) {
                int sn = __shfl(id, j + 1, 64);
                wn = KVp[(size_t)sn * 64 + l];
            }
            float2 f0 = __half22float2(w.a);
            float2 f1 = __half22float2(w.b);
            float p = f0.x * qf.x + f0.y * qf.y + f1.x * qf.z + f1.y * qf.w;
            p += __shfl_xor(p, 1, 64);
            p += __shfl_xor(p, 2, 64);
            float sc = __expf(fminf(5.f, fmaxf(-5.f, p * 0.25f)));
            zacc += sc;
            float scv = __shfl(sc, srcl, 64);
            a0 = fmaf(f0.x, scv, a0); a1 = fmaf(f0.y, scv, a1);
            a2 = fmaf(f1.x, scv, a2); a3 = fmaf(f1.y, scv, a3);
            w = wn;
        }
    }

    // per-head normalize, then mean over heads
    const float zh = __shfl(zacc, srcl, 64);
    float r0 = a0 / zh, r1 = a1 / zh, r2 = a2 / zh, r3 = a3 / zh;
#pragma unroll
    for (int m = 4; m <= 16; m <<= 1) {
        r0 += __shfl_xor(r0, m, 64);
        r1 += __shfl_xor(r1, m, 64);
        r2 += __shfl_xor(r2, m, 64);
        r3 += __shfl_xor(r3, m, 64);
    }
    if (l >= 32 && l < 36)
        ((float4*)(out + (size_t)n * OD))[l - 32] =
            make_float4(r0 * 0.125f, r1 * 0.125f, r2 * 0.125f, r3 * 0.125f);
}

// ---------------- launch ------------------------------------------------------
extern "C" void kernel_launch(void* const* d_in, const int* in_sizes, int n_in,
                              void* d_out, int out_size, void* d_ws, size_t ws_size,
                              hipStream_t stream)
{
    const float* h  = (const float*)d_in[0];
    const float* Qw = (const float*)d_in[1];
    const float* Qb = (const float*)d_in[2];
    const float* Kw = (const float*)d_in[3];
    const float* Kb = (const float*)d_in[4];
    const float* Vw = (const float*)d_in[5];
    const float* Vb = (const float*)d_in[6];
    const int*   src = (const int*)d_in[7];
    const int*   dst = (const int*)d_in[8];

    char* ws = (char*)d_ws;
    _Float16* h16  = (_Float16*)ws;                    ws += (size_t)50048 * IND * 2;  // padded rows for last tile
    _Float16* W16  = (_Float16*)ws;                    ws += (size_t)NOUT * IND * 2;
    float*    b_all = (float*)ws;                      ws += 288 * 4;
    __half*   KVbuf = (__half*)ws;                     ws += (size_t)NNODES * 256 * 2;
    float*    Qs    = (float*)ws;                      ws += (size_t)NNODES * OD * 4;
    int*      count  = (int*)ws;                       ws += (size_t)NNODES * 4;
    int*      incl   = (int*)ws;                       ws += (size_t)NNODES * 4;
    int*      offs   = (int*)ws;                       ws += (size_t)NNODES * 4;
    int*      cursor = (int*)ws;                       ws += (size_t)NNODES * 4;
    int*      bsum   = (int*)ws;                       ws += 256 * 4;
    int*      eidx   = (int*)ws;                       ws += (size_t)NEDGE * 4;

    hipMemsetAsync(count, 0, (size_t)NNODES * 4, stream);

    conv_hist_kernel<<<HB2 + CB + 1, 256, 0, stream>>>(
        h, Qw, Qb, Kw, Kb, Vw, Vb, dst, h16, W16, b_all, count);

    proj_mfma_kernel<<<PB2, 256, 0, stream>>>(h16, W16, b_all, KVbuf, Qs);

    scan1_kernel<<<NB1, 256, 0, stream>>>(count, incl, bsum);
    scan2_kernel<<<1, 256, 0, stream>>>(bsum);
    scan3_kernel<<<NB1, 256, 0, stream>>>(count, incl, bsum, offs, cursor);
    scatter_kernel<<<HB2, 256, 0, stream>>>(src, dst, cursor, eidx);

    gather_kernel<<<(NNODES + 3) / 4, 256, 0, stream>>>(
        KVbuf, Qs, offs, count, eidx, (float*)d_out);
}

// Round 6
// 346.875 us; speedup vs baseline: 1.4072x; 1.4072x over previous
//
#include <hip/hip_runtime.h>
#include <hip/hip_fp16.h>
#include <math.h>

#define NNODES 50000
#define IND    128
#define NH     8
#define OD     16
#define HD     128          // NH*OD
#define NEDGE  1600000
#define NOUT   272          // 128 K + 128 V + 16 Qsum = 17 n-tiles of 16
#define NBUCK  196          // dst>>8 buckets (256 nodes each)
#define P1B    782          // ceil(NEDGE/2048) edge-chunk blocks
#define CB     3125         // h->fp16 convert blocks (8 floats/thread)
#define PB2    ((NNODES + 63) / 64)      // 782 MFMA-proj blocks (64 rows each)

typedef _Float16 half8  __attribute__((ext_vector_type(8)));
typedef float    floatx4 __attribute__((ext_vector_type(4)));

struct h2x2 { __half2 a, b; };           // one 8B packed load: 4 fp16

// ---------------- Fused: bucket-count pass1 + h->fp16 convert + W16 build -----
// Blocks [0,P1B): per-block LDS bucket histogram of 2048 edges -> 196 global
// atomics per block. Blocks [P1B,P1B+CB): h->fp16. Last block: W16/b_all.
__global__ __launch_bounds__(256) void conv_p1_kernel(
    const float* __restrict__ hmat,
    const float* __restrict__ Qw, const float* __restrict__ Qb,
    const float* __restrict__ Kw, const float* __restrict__ Kb,
    const float* __restrict__ Vw, const float* __restrict__ Vb,
    const int* __restrict__ dst,
    _Float16* __restrict__ h16, _Float16* __restrict__ W16,
    float* __restrict__ b_all, int* __restrict__ bcount_g)
{
    const int bid = blockIdx.x;
    const int t   = threadIdx.x;

    if (bid < P1B) {                                   // pass 1: bucket count
        __shared__ int bcnt[256];
        bcnt[t] = 0;
        __syncthreads();
#pragma unroll
        for (int j = 0; j < 8; j++) {
            int e = bid * 2048 + j * 256 + t;
            if (e < NEDGE) atomicAdd(&bcnt[dst[e] >> 8], 1);
        }
        __syncthreads();
        if (t < NBUCK && bcnt[t]) atomicAdd(&bcount_g[t], bcnt[t]);
        return;
    }
    if (bid < P1B + CB) {                              // h -> fp16
        const size_t i = (size_t)(bid - P1B) * 256 + t;  // 8 floats each
        const float4* hp = (const float4*)hmat;
        float4 x = hp[i * 2];
        float4 y = hp[i * 2 + 1];
        half8 o;
        o[0] = (_Float16)x.x; o[1] = (_Float16)x.y;
        o[2] = (_Float16)x.z; o[3] = (_Float16)x.w;
        o[4] = (_Float16)y.x; o[5] = (_Float16)y.y;
        o[6] = (_Float16)y.z; o[7] = (_Float16)y.w;
        *(half8*)(h16 + i * 8) = o;
        return;
    }
    // single block: build W16 = [Kw | Vw | sum_h Qw] fp16 and b_all fp32
    for (int i = t; i < NOUT * IND; i += 256) {
        int r = i >> 7, c = i & 127;
        float v;
        if (r < 128)       v = Kw[i];
        else if (r < 256)  v = Vw[i - 128 * IND];
        else {
            v = 0.f;
#pragma unroll
            for (int hh = 0; hh < NH; hh++) v += Qw[((hh << 4) + (r - 256)) * IND + c];
        }
        W16[i] = (_Float16)v;
    }
    for (int i = t; i < NOUT; i += 256) {
        float v;
        if (i < 128)      v = Kb[i];
        else if (i < 256) v = Vb[i - 128];
        else {
            v = 0.f;
#pragma unroll
            for (int hh = 0; hh < NH; hh++) v += Qb[(hh << 4) + (i - 256)];
        }
        b_all[i] = v;
    }
}

// ---------------- bucket scan (1 block) ---------------------------------------
__global__ __launch_bounds__(256) void bscan_kernel(
    const int* __restrict__ bcount_g,
    int* __restrict__ bucket_base, int* __restrict__ bucket_cursor)
{
    __shared__ int sd[256];
    const int t = threadIdx.x;
    const int c = (t < NBUCK) ? bcount_g[t] : 0;
    sd[t] = c;
    __syncthreads();
    for (int ofs = 1; ofs < 256; ofs <<= 1) {
        int x = (t >= ofs) ? sd[t - ofs] : 0;
        __syncthreads();
        sd[t] += x;
        __syncthreads();
    }
    if (t < NBUCK) {
        int excl = sd[t] - c;
        bucket_base[t]   = excl;
        bucket_cursor[t] = excl;
        if (t == NBUCK - 1) bucket_base[NBUCK] = sd[t];
    }
}

// ---------------- Fused: pass2 bucket-scatter + MFMA projection ---------------
// Blocks [0,P1B): stage 2048 edges in LDS packed (b<<24)|(src<<8)|dlow,
// reserve per-bucket ranges (1 atomic per block-bucket), write bucket-
// contiguous runs to ebuck. Blocks [P1B,P1B+PB2): MFMA projection
// [50000x128]@[128x272]; A-frags in regs, B streamed from L2-hot W16.
// A: lane l holds A[m=l&15][k=(l>>4)*8+j]; C/D: col=l&15, row=(l>>4)*4+reg.
__global__ __launch_bounds__(256) void p2_proj_kernel(
    const int* __restrict__ src, const int* __restrict__ dst,
    int* __restrict__ bucket_cursor, unsigned int* __restrict__ ebuck,
    const _Float16* __restrict__ h16, const _Float16* __restrict__ W16,
    const float* __restrict__ b_all,
    __half* __restrict__ KVbuf, float* __restrict__ Qs)
{
    const int t = threadIdx.x;

    if (blockIdx.x < P1B) {                            // pass 2
        __shared__ unsigned int epk[2048];
        __shared__ int bcnt[256];
        __shared__ int bcur[256];
        bcnt[t] = 0;
        __syncthreads();
#pragma unroll
        for (int j = 0; j < 8; j++) {
            int e = blockIdx.x * 2048 + j * 256 + t;
            if (e < NEDGE) {
                int s = src[e], d = dst[e];
                unsigned int b = (unsigned int)d >> 8;
                epk[j * 256 + t] = (b << 24) | ((unsigned int)s << 8) | (d & 255);
                atomicAdd(&bcnt[b], 1);
            }
        }
        __syncthreads();
        if (t < NBUCK && bcnt[t]) bcur[t] = atomicAdd(&bucket_cursor[t], bcnt[t]);
        __syncthreads();
#pragma unroll
        for (int j = 0; j < 8; j++) {
            int e = blockIdx.x * 2048 + j * 256 + t;
            if (e < NEDGE) {
                unsigned int v = epk[j * 256 + t];
                int r = atomicAdd(&bcur[v >> 24], 1);
                ebuck[r] = v;
            }
        }
        return;
    }

    // MFMA projection
    const int pbid = blockIdx.x - P1B;
    const int wave = t >> 6;
    const int l    = t & 63;
    const int cl   = l & 15;
    const int quad = l >> 4;
    const int m0   = pbid * 64 + wave * 16;

    const _Float16* ab = h16 + (size_t)(m0 + cl) * IND + quad * 8;
    half8 afrag[4];
#pragma unroll
    for (int ks = 0; ks < 4; ks++) afrag[ks] = *(const half8*)(ab + ks * 32);

    const int rowbase = m0 + quad * 4;

#pragma unroll 4
    for (int ti = 0; ti < 17; ti++) {
        const _Float16* wb = W16 + (size_t)(ti * 16 + cl) * IND + quad * 8;
        floatx4 acc = {0.f, 0.f, 0.f, 0.f};
#pragma unroll
        for (int ks = 0; ks < 4; ks++)
            acc = __builtin_amdgcn_mfma_f32_16x16x32_f16(
                afrag[ks], *(const half8*)(wb + ks * 32), acc, 0, 0, 0);

        const float bias = b_all[ti * 16 + cl];
        if (ti < 16) {
            const int col = ti * 16 + cl;
#pragma unroll
            for (int r = 0; r < 4; r++) {
                int node = rowbase + r;
                if (node < NNODES)
                    KVbuf[(size_t)node * 256 + col] = __float2half_rn(acc[r] + bias);
            }
        } else {
#pragma unroll
            for (int r = 0; r < 4; r++) {
                int node = rowbase + r;
                if (node < NNODES)
                    Qs[(size_t)node * OD + cl] = acc[r] + bias;
            }
        }
    }
}

// ---------------- Pass 3: per-bucket node grouping -> offs/count/eidx16 -------
__global__ __launch_bounds__(256) void p3_kernel(
    const unsigned int* __restrict__ ebuck,
    const int* __restrict__ bucket_base,
    int* __restrict__ offs, int* __restrict__ count,
    unsigned short* __restrict__ eidx16)
{
    __shared__ int cnt[256];
    __shared__ int sd[256];
    __shared__ int cur[256];
    const int b  = blockIdx.x;
    const int t  = threadIdx.x;
    const int n0 = b << 8;
    const int start = bucket_base[b];
    const int end   = bucket_base[b + 1];

    cnt[t] = 0;
    __syncthreads();
    for (int i = start + t; i < end; i += 256)
        atomicAdd(&cnt[ebuck[i] & 255], 1);
    __syncthreads();

    const int c = cnt[t];
    sd[t] = c;
    __syncthreads();
    for (int ofs = 1; ofs < 256; ofs <<= 1) {
        int x = (t >= ofs) ? sd[t - ofs] : 0;
        __syncthreads();
        sd[t] += x;
        __syncthreads();
    }
    const int excl = sd[t] - c;
    const int node = n0 + t;
    if (node < NNODES) {
        offs[node]  = start + excl;
        count[node] = c;
    }
    cur[t] = start + excl;
    __syncthreads();

    for (int i = start + t; i < end; i += 256) {
        unsigned int v = ebuck[i];
        int r = atomicAdd(&cur[v & 255], 1);
        eidx16[r] = (unsigned short)(v >> 8);
    }
}

// ---------------- Gather-reduce: one wave per destination node ----------------
// Packed fp16 KV row = 512B = 64 h2x2: lane l loads half-elems [4l,4l+3]
// (lanes 0-31 = K, lanes 32-63 = V). Score on K lanes (head l>>2, xor{1,2});
// V lanes grab the score via shfl from K lane (l&28) and keep 4 accumulators.
__global__ __launch_bounds__(256) void gather_kernel(
    const __half* __restrict__ KVbuf, const float* __restrict__ Qs,
    const int* __restrict__ offs, const int* __restrict__ count,
    const unsigned short* __restrict__ eidx16,
    float* __restrict__ out)
{
    const int n = blockIdx.x * 4 + (threadIdx.x >> 6);
    const int l = threadIdx.x & 63;
    if (n >= NNODES) return;

    const h2x2* KVp = (const h2x2*)KVbuf;          // 64 h2x2 per node row
    const float4 qf = ((const float4*)(Qs + (size_t)n * OD))[l & 3];
    const int srcl = (l & 32) ? (l & 28) : l;       // V lane -> K lane 4*head

    const int off = offs[n];
    const int cnt = count[n];

    float a0 = 0.f, a1 = 0.f, a2 = 0.f, a3 = 0.f, zacc = 0.f;

    // self-loop (s = n)
    {
        h2x2 w = KVp[(size_t)n * 64 + l];
        float2 f0 = __half22float2(w.a);
        float2 f1 = __half22float2(w.b);
        float p = f0.x * qf.x + f0.y * qf.y + f1.x * qf.z + f1.y * qf.w;
        p += __shfl_xor(p, 1, 64);
        p += __shfl_xor(p, 2, 64);
        float sc = __expf(fminf(5.f, fmaxf(-5.f, p * 0.25f)));
        zacc += sc;
        float scv = __shfl(sc, srcl, 64);
        a0 = fmaf(f0.x, scv, a0); a1 = fmaf(f0.y, scv, a1);
        a2 = fmaf(f1.x, scv, a2); a3 = fmaf(f1.y, scv, a3);
    }

    for (int base = 0; base < cnt; base += 64) {
        const int m  = min(64, cnt - base);
        const int id = (base + l < cnt) ? (int)eidx16[off + base + l] : 0;

        int s0 = __shfl(id, 0, 64);
        h2x2 w = KVp[(size_t)s0 * 64 + l];

        for (int j = 0; j < m; j++) {
            h2x2 wn = w;
            if (j + 1 < m) {
                int sn = __shfl(id, j + 1, 64);
                wn = KVp[(size_t)sn * 64 + l];
            }
            float2 f0 = __half22float2(w.a);
            float2 f1 = __half22float2(w.b);
            float p = f0.x * qf.x + f0.y * qf.y + f1.x * qf.z + f1.y * qf.w;
            p += __shfl_xor(p, 1, 64);
            p += __shfl_xor(p, 2, 64);
            float sc = __expf(fminf(5.f, fmaxf(-5.f, p * 0.25f)));
            zacc += sc;
            float scv = __shfl(sc, srcl, 64);
            a0 = fmaf(f0.x, scv, a0); a1 = fmaf(f0.y, scv, a1);
            a2 = fmaf(f1.x, scv, a2); a3 = fmaf(f1.y, scv, a3);
            w = wn;
        }
    }

    // per-head normalize, then mean over heads
    const float zh = __shfl(zacc, srcl, 64);
    float r0 = a0 / zh, r1 = a1 / zh, r2 = a2 / zh, r3 = a3 / zh;
#pragma unroll
    for (int m = 4; m <= 16; m <<= 1) {
        r0 += __shfl_xor(r0, m, 64);
        r1 += __shfl_xor(r1, m, 64);
        r2 += __shfl_xor(r2, m, 64);
        r3 += __shfl_xor(r3, m, 64);
    }
    if (l >= 32 && l < 36)
        ((float4*)(out + (size_t)n * OD))[l - 32] =
            make_float4(r0 * 0.125f, r1 * 0.125f, r2 * 0.125f, r3 * 0.125f);
}

// ---------------- launch ------------------------------------------------------
extern "C" void kernel_launch(void* const* d_in, const int* in_sizes, int n_in,
                              void* d_out, int out_size, void* d_ws, size_t ws_size,
                              hipStream_t stream)
{
    const float* h  = (const float*)d_in[0];
    const float* Qw = (const float*)d_in[1];
    const float* Qb = (const float*)d_in[2];
    const float* Kw = (const float*)d_in[3];
    const float* Kb = (const float*)d_in[4];
    const float* Vw = (const float*)d_in[5];
    const float* Vb = (const float*)d_in[6];
    const int*   src = (const int*)d_in[7];
    const int*   dst = (const int*)d_in[8];

    char* ws = (char*)d_ws;
    _Float16* h16  = (_Float16*)ws;                    ws += (size_t)50048 * IND * 2;  // padded rows
    _Float16* W16  = (_Float16*)ws;                    ws += (size_t)NOUT * IND * 2;
    float*    b_all = (float*)ws;                      ws += 288 * 4;
    __half*   KVbuf = (__half*)ws;                     ws += (size_t)NNODES * 256 * 2;
    float*    Qs    = (float*)ws;                      ws += (size_t)NNODES * OD * 4;
    int*      offs   = (int*)ws;                       ws += (size_t)NNODES * 4;
    int*      count  = (int*)ws;                       ws += (size_t)NNODES * 4;
    int*      bcount_g      = (int*)ws;                ws += 256 * 4;
    int*      bucket_base   = (int*)ws;                ws += 256 * 4;
    int*      bucket_cursor = (int*)ws;                ws += 256 * 4;
    unsigned int*   ebuck  = (unsigned int*)ws;        ws += (size_t)NEDGE * 4;
    unsigned short* eidx16 = (unsigned short*)ws;      ws += (size_t)NEDGE * 2;

    hipMemsetAsync(bcount_g, 0, 256 * 4, stream);

    conv_p1_kernel<<<P1B + CB + 1, 256, 0, stream>>>(
        h, Qw, Qb, Kw, Kb, Vw, Vb, dst, h16, W16, b_all, bcount_g);

    bscan_kernel<<<1, 256, 0, stream>>>(bcount_g, bucket_base, bucket_cursor);

    p2_proj_kernel<<<P1B + PB2, 256, 0, stream>>>(
        src, dst, bucket_cursor, ebuck, h16, W16, b_all, KVbuf, Qs);

    p3_kernel<<<NBUCK, 256, 0, stream>>>(ebuck, bucket_base, offs, count, eidx16);

    gather_kernel<<<(NNODES + 3) / 4, 256, 0, stream>>>(
        KVbuf, Qs, offs, count, eidx16, (float*)d_out);
}

// Round 7
// 309.204 us; speedup vs baseline: 1.5786x; 1.1218x over previous
//
#include <hip/hip_runtime.h>
#include <hip/hip_fp16.h>
#include <math.h>

#define NNODES 50000
#define IND    128
#define NH     8
#define OD     16
#define NEDGE  1600000
#define NOUT   272          // 128 K + 128 V + 16 Qsum
#define NBUCK  196          // dst>>8 buckets
#define BCAP   9216         // per-bucket region capacity (mean 8192, sigma~90)
#define P1B    782          // edge chunks of 2048
#define CB     3125         // h->fp16 convert blocks
#define PB2    782          // ceil(50000/64) MFMA-proj blocks

typedef _Float16 half8  __attribute__((ext_vector_type(8)));
typedef float    floatx4 __attribute__((ext_vector_type(4)));

struct h2x2 { __half2 a, b; };           // one 8B packed load: 4 fp16

// ---------------- K1: h->fp16 convert + W16/b_all build + cursor init ---------
__global__ __launch_bounds__(256) void k1_conv(
    const float* __restrict__ hmat,
    const float* __restrict__ Qw, const float* __restrict__ Qb,
    const float* __restrict__ Kw, const float* __restrict__ Kb,
    const float* __restrict__ Vw, const float* __restrict__ Vb,
    _Float16* __restrict__ h16, _Float16* __restrict__ W16,
    float* __restrict__ b_all, int* __restrict__ cursor)
{
    const int bid = blockIdx.x;
    const int t   = threadIdx.x;

    if (bid < CB) {                                    // h -> fp16, 8 floats/thread
        const size_t i = (size_t)bid * 256 + t;
        const float4* hp = (const float4*)hmat;
        float4 x = hp[i * 2];
        float4 y = hp[i * 2 + 1];
        half8 o;
        o[0] = (_Float16)x.x; o[1] = (_Float16)x.y;
        o[2] = (_Float16)x.z; o[3] = (_Float16)x.w;
        o[4] = (_Float16)y.x; o[5] = (_Float16)y.y;
        o[6] = (_Float16)y.z; o[7] = (_Float16)y.w;
        *(half8*)(h16 + i * 8) = o;
        return;
    }
    // last block: W16 = [Kw | Vw | sum_h Qw] fp16, b_all fp32, bucket cursors
    for (int i = t; i < NOUT * IND; i += 256) {
        int r = i >> 7, c = i & 127;
        float v;
        if (r < 128)       v = Kw[i];
        else if (r < 256)  v = Vw[i - 128 * IND];
        else {
            v = 0.f;
#pragma unroll
            for (int hh = 0; hh < NH; hh++) v += Qw[((hh << 4) + (r - 256)) * IND + c];
        }
        W16[i] = (_Float16)v;
    }
    for (int i = t; i < NOUT; i += 256) {
        float v;
        if (i < 128)      v = Kb[i];
        else if (i < 256) v = Vb[i - 128];
        else {
            v = 0.f;
#pragma unroll
            for (int hh = 0; hh < NH; hh++) v += Qb[(hh << 4) + (i - 256)];
        }
        b_all[i] = v;
    }
    if (t < NBUCK) cursor[t] = t * BCAP;
}

// ---------------- K2: bucket scatter (block-local counting sort) + MFMA proj --
// Blocks [0,P1B): stage 2048 edges, count per bucket in LDS, block-local
// counting sort, reserve per-bucket global ranges (1 atomic per block-bucket),
// write bucket runs contiguously. Blocks [P1B,P1B+PB2): MFMA projection
// [50000x128]@[128x272]. A: lane l holds A[m=l&15][k=(l>>4)*8+j];
// C/D: col=l&15, row=(l>>4)*4+reg.
__global__ __launch_bounds__(256) void k2_scatter_proj(
    const int* __restrict__ src, const int* __restrict__ dst,
    int* __restrict__ cursor, unsigned int* __restrict__ ebuck,
    const _Float16* __restrict__ h16, const _Float16* __restrict__ W16,
    const float* __restrict__ b_all,
    __half* __restrict__ KVbuf, float* __restrict__ Qs)
{
    const int t = threadIdx.x;

    if (blockIdx.x < P1B) {
        __shared__ unsigned int epk[2048];
        __shared__ unsigned int sorted[2048];
        __shared__ int bcnt[256];
        __shared__ int sd[256];
        __shared__ int baseg[256];
        __shared__ int rk[256];

        const int e0 = blockIdx.x * 2048;
        const int ne = min(2048, NEDGE - e0);

        bcnt[t] = 0; rk[t] = 0;
        __syncthreads();
#pragma unroll
        for (int j = 0; j < 8; j++) {
            int idx = j * 256 + t;
            if (idx < ne) {
                int s = src[e0 + idx], d = dst[e0 + idx];
                unsigned int b = (unsigned int)d >> 8;
                epk[idx] = (b << 24) | ((unsigned int)s << 8) | (d & 255);
                atomicAdd(&bcnt[b], 1);
            }
        }
        __syncthreads();
        sd[t] = bcnt[t];
        __syncthreads();
        for (int ofs = 1; ofs < 256; ofs <<= 1) {
            int x = (t >= ofs) ? sd[t - ofs] : 0;
            __syncthreads();
            sd[t] += x;
            __syncthreads();
        }
        if (t < NBUCK && bcnt[t]) baseg[t] = atomicAdd(&cursor[t], bcnt[t]);
        sd[t] -= bcnt[t];                    // exclusive prefix (own element)
        __syncthreads();
#pragma unroll
        for (int j = 0; j < 8; j++) {
            int idx = j * 256 + t;
            if (idx < ne) {
                unsigned int v = epk[idx];
                int b = v >> 24;
                int r = atomicAdd(&rk[b], 1);
                sorted[sd[b] + r] = v;
            }
        }
        __syncthreads();
        for (int i = t; i < ne; i += 256) {
            unsigned int v = sorted[i];
            int b = v >> 24;
            ebuck[baseg[b] + (i - sd[b])] = v;   // contiguous per-bucket runs
        }
        return;
    }

    // MFMA projection
    const int pbid = blockIdx.x - P1B;
    const int wave = t >> 6;
    const int l    = t & 63;
    const int cl   = l & 15;
    const int quad = l >> 4;
    const int m0   = pbid * 64 + wave * 16;

    const _Float16* ab = h16 + (size_t)(m0 + cl) * IND + quad * 8;
    half8 afrag[4];
#pragma unroll
    for (int ks = 0; ks < 4; ks++) afrag[ks] = *(const half8*)(ab + ks * 32);

    const int rowbase = m0 + quad * 4;

#pragma unroll 4
    for (int ti = 0; ti < 17; ti++) {
        const _Float16* wb = W16 + (size_t)(ti * 16 + cl) * IND + quad * 8;
        floatx4 acc = {0.f, 0.f, 0.f, 0.f};
#pragma unroll
        for (int ks = 0; ks < 4; ks++)
            acc = __builtin_amdgcn_mfma_f32_16x16x32_f16(
                afrag[ks], *(const half8*)(wb + ks * 32), acc, 0, 0, 0);

        const float bias = b_all[ti * 16 + cl];
        if (ti < 16) {
            const int col = ti * 16 + cl;
#pragma unroll
            for (int r = 0; r < 4; r++) {
                int node = rowbase + r;
                if (node < NNODES)
                    KVbuf[(size_t)node * 256 + col] = __float2half_rn(acc[r] + bias);
            }
        } else {
#pragma unroll
            for (int r = 0; r < 4; r++) {
                int node = rowbase + r;
                if (node < NNODES)
                    Qs[(size_t)node * OD + cl] = acc[r] + bias;
            }
        }
    }
}

// ---------------- K3: per-bucket node grouping -> offs/count/eidx16 -----------
__global__ __launch_bounds__(256) void k3_group(
    const unsigned int* __restrict__ ebuck, const int* __restrict__ cursor,
    int* __restrict__ offs, int* __restrict__ count,
    unsigned short* __restrict__ eidx16)
{
    __shared__ int cnt[256];
    __shared__ int sd[256];
    __shared__ int cur[256];
    const int b  = blockIdx.x;
    const int t  = threadIdx.x;
    const int n0 = b << 8;
    const int start = b * BCAP;
    const int end   = cursor[b];

    cnt[t] = 0;
    __syncthreads();
    for (int i = start + t; i < end; i += 256)
        atomicAdd(&cnt[ebuck[i] & 255], 1);
    __syncthreads();

    const int c = cnt[t];
    sd[t] = c;
    __syncthreads();
    for (int ofs = 1; ofs < 256; ofs <<= 1) {
        int x = (t >= ofs) ? sd[t - ofs] : 0;
        __syncthreads();
        sd[t] += x;
        __syncthreads();
    }
    const int excl = sd[t] - c;
    const int node = n0 + t;
    if (node < NNODES) {
        offs[node]  = start + excl;
        count[node] = c;
    }
    cur[t] = start + excl;
    __syncthreads();

    for (int i = start + t; i < end; i += 256) {
        unsigned int v = ebuck[i];
        int r = atomicAdd(&cur[v & 255], 1);
        eidx16[r] = (unsigned short)((v >> 8) & 0xFFFF);
    }
}

// ---------------- K4: gather-reduce, 32 lanes/edge, 2 edges in flight ---------
// Lane l: half_id=l>>5, lh=l&31. Lane owns K halves [4lh,4lh+3] AND V halves
// [4lh,4lh+3] of head lh>>2 for its half's edge. Score: 4 MACs + xor{1,2}
// (within 4-lane head group); score stays on the lanes that apply it to V.
// Self-loop = virtual stream element 0. Epilogue: half-sum (xor32),
// normalize, head-mean (xor 4,8,16), lanes 0-3 write float4.
__global__ __launch_bounds__(256) void k4_gather(
    const __half* __restrict__ KVbuf, const float* __restrict__ Qs,
    const int* __restrict__ offs, const int* __restrict__ count,
    const unsigned short* __restrict__ eidx16,
    float* __restrict__ out)
{
    const int n = blockIdx.x * 4 + (threadIdx.x >> 6);
    const int l = threadIdx.x & 63;
    if (n >= NNODES) return;

    const int lh      = l & 31;
    const int half_id = l >> 5;

    const h2x2* KVp = (const h2x2*)KVbuf;            // 64 h2x2 per node row
    const float4 qf = ((const float4*)(Qs + (size_t)n * OD))[lh & 3];

    const int off   = offs[n];
    const int total = count[n] + 1;                  // + self-loop

    float a0 = 0.f, a1 = 0.f, a2 = 0.f, a3 = 0.f, zacc = 0.f;

    for (int base = 0; base < total; base += 64) {
        const int gi = base + l;
        int id = n;                                  // gi==0 -> self-loop
        if (gi > 0) id = (gi < total) ? (int)eidx16[off + gi - 1] : 0;

        int steps = total - base;
        if (steps > 64) steps = 64;

        int sn = __shfl(id, half_id, 64);
        h2x2 kc = KVp[(size_t)sn * 64 + lh];
        h2x2 vc = KVp[(size_t)sn * 64 + 32 + lh];

        for (int j = 0; j < steps; j += 2) {
            int nxt = j + 2 + half_id;
            int snn = __shfl(id, (nxt < 64) ? nxt : 0, 64);
            h2x2 kn = KVp[(size_t)snn * 64 + lh];
            h2x2 vn = KVp[(size_t)snn * 64 + 32 + lh];

            float2 f0 = __half22float2(kc.a);
            float2 f1 = __half22float2(kc.b);
            float p = f0.x * qf.x + f0.y * qf.y + f1.x * qf.z + f1.y * qf.w;
            p += __shfl_xor(p, 1, 64);
            p += __shfl_xor(p, 2, 64);
            float sc = __expf(fminf(5.f, fmaxf(-5.f, p * 0.25f)));
            sc = (j + half_id < steps) ? sc : 0.f;

            float2 g0 = __half22float2(vc.a);
            float2 g1 = __half22float2(vc.b);
            zacc += sc;
            a0 = fmaf(g0.x, sc, a0); a1 = fmaf(g0.y, sc, a1);
            a2 = fmaf(g1.x, sc, a2); a3 = fmaf(g1.y, sc, a3);

            kc = kn; vc = vn;
        }
    }

    // combine the two edge-halves
    zacc += __shfl_xor(zacc, 32, 64);
    a0 += __shfl_xor(a0, 32, 64);
    a1 += __shfl_xor(a1, 32, 64);
    a2 += __shfl_xor(a2, 32, 64);
    a3 += __shfl_xor(a3, 32, 64);

    // per-head normalize, then mean over heads (xor over head bits 2,3,4)
    const float inv = 1.f / zacc;
    float r0 = a0 * inv, r1 = a1 * inv, r2 = a2 * inv, r3 = a3 * inv;
#pragma unroll
    for (int m = 4; m <= 16; m <<= 1) {
        r0 += __shfl_xor(r0, m, 64);
        r1 += __shfl_xor(r1, m, 64);
        r2 += __shfl_xor(r2, m, 64);
        r3 += __shfl_xor(r3, m, 64);
    }
    if (l < 4)
        ((float4*)(out + (size_t)n * OD))[l] =
            make_float4(r0 * 0.125f, r1 * 0.125f, r2 * 0.125f, r3 * 0.125f);
}

// ---------------- launch ------------------------------------------------------
extern "C" void kernel_launch(void* const* d_in, const int* in_sizes, int n_in,
                              void* d_out, int out_size, void* d_ws, size_t ws_size,
                              hipStream_t stream)
{
    const float* h  = (const float*)d_in[0];
    const float* Qw = (const float*)d_in[1];
    const float* Qb = (const float*)d_in[2];
    const float* Kw = (const float*)d_in[3];
    const float* Kb = (const float*)d_in[4];
    const float* Vw = (const float*)d_in[5];
    const float* Vb = (const float*)d_in[6];
    const int*   src = (const int*)d_in[7];
    const int*   dst = (const int*)d_in[8];

    char* ws = (char*)d_ws;
    _Float16* h16  = (_Float16*)ws;                    ws += (size_t)50048 * IND * 2;
    _Float16* W16  = (_Float16*)ws;                    ws += (size_t)NOUT * IND * 2;
    float*    b_all = (float*)ws;                      ws += 288 * 4;
    __half*   KVbuf = (__half*)ws;                     ws += (size_t)NNODES * 256 * 2;
    float*    Qs    = (float*)ws;                      ws += (size_t)NNODES * OD * 4;
    int*      offs   = (int*)ws;                       ws += (size_t)NNODES * 4;
    int*      count  = (int*)ws;                       ws += (size_t)NNODES * 4;
    int*      cursor = (int*)ws;                       ws += 256 * 4;
    unsigned int*   ebuck  = (unsigned int*)ws;        ws += (size_t)NBUCK * BCAP * 4;
    unsigned short* eidx16 = (unsigned short*)ws;      ws += (size_t)NBUCK * BCAP * 2;

    k1_conv<<<CB + 1, 256, 0, stream>>>(
        h, Qw, Qb, Kw, Kb, Vw, Vb, h16, W16, b_all, cursor);

    k2_scatter_proj<<<P1B + PB2, 256, 0, stream>>>(
        src, dst, cursor, ebuck, h16, W16, b_all, KVbuf, Qs);

    k3_group<<<NBUCK, 256, 0, stream>>>(ebuck, cursor, offs, count, eidx16);

    k4_gather<<<(NNODES + 3) / 4, 256, 0, stream>>>(
        KVbuf, Qs, offs, count, eidx16, (float*)d_out);
}

// Round 8
// 298.441 us; speedup vs baseline: 1.6355x; 1.0361x over previous
//
#include <hip/hip_runtime.h>
#include <hip/hip_fp16.h>
#include <math.h>

#define NNODES 50000
#define IND    128
#define NH     8
#define OD     16
#define NEDGE  1600000
#define NOUT   272           // 128 K + 128 V + 16 Qsum
#define NBUCK  782           // dst>>6 buckets (64 nodes each)
#define BCAP   2560          // per-bucket capacity (mean 2046, +11 sigma); 10*256
#define P1B    782           // edge chunks of 2048
#define CB     3125          // h->fp16 convert blocks
#define PB2    782           // ceil(50000/64) MFMA-proj blocks

typedef _Float16 half8 __attribute__((ext_vector_type(8)));
typedef _Float16 h2t   __attribute__((ext_vector_type(2)));
typedef float    floatx4 __attribute__((ext_vector_type(4)));

static __device__ __forceinline__ h2t u2h(unsigned int u) {
    union { unsigned int u; h2t h; } x; x.u = u; return x.h;
}
static __device__ __forceinline__ float qdot(uint4 k, uint4 q, float p) {
    p = __builtin_amdgcn_fdot2(u2h(k.x), u2h(q.x), p, false);
    p = __builtin_amdgcn_fdot2(u2h(k.y), u2h(q.y), p, false);
    p = __builtin_amdgcn_fdot2(u2h(k.z), u2h(q.z), p, false);
    p = __builtin_amdgcn_fdot2(u2h(k.w), u2h(q.w), p, false);
    return p;
}
// acc[d] += vA[d]*scA + vB[d]*scB for 8 dims, fp32 accumulators.
static __device__ __forceinline__ void vacc8(uint4 vA, uint4 vB, h2t sc2, float* acc) {
    unsigned lo, hi;
    lo = __builtin_amdgcn_perm(vB.x, vA.x, 0x05040100u);
    hi = __builtin_amdgcn_perm(vB.x, vA.x, 0x07060302u);
    acc[0] = __builtin_amdgcn_fdot2(u2h(lo), sc2, acc[0], false);
    acc[1] = __builtin_amdgcn_fdot2(u2h(hi), sc2, acc[1], false);
    lo = __builtin_amdgcn_perm(vB.y, vA.y, 0x05040100u);
    hi = __builtin_amdgcn_perm(vB.y, vA.y, 0x07060302u);
    acc[2] = __builtin_amdgcn_fdot2(u2h(lo), sc2, acc[2], false);
    acc[3] = __builtin_amdgcn_fdot2(u2h(hi), sc2, acc[3], false);
    lo = __builtin_amdgcn_perm(vB.z, vA.z, 0x05040100u);
    hi = __builtin_amdgcn_perm(vB.z, vA.z, 0x07060302u);
    acc[4] = __builtin_amdgcn_fdot2(u2h(lo), sc2, acc[4], false);
    acc[5] = __builtin_amdgcn_fdot2(u2h(hi), sc2, acc[5], false);
    lo = __builtin_amdgcn_perm(vB.w, vA.w, 0x05040100u);
    hi = __builtin_amdgcn_perm(vB.w, vA.w, 0x07060302u);
    acc[6] = __builtin_amdgcn_fdot2(u2h(lo), sc2, acc[6], false);
    acc[7] = __builtin_amdgcn_fdot2(u2h(hi), sc2, acc[7], false);
}

// ---------------- K1: h->fp16 convert + W16/b_all build + cursor init ---------
__global__ __launch_bounds__(256) void k1_conv(
    const float* __restrict__ hmat,
    const float* __restrict__ Qw, const float* __restrict__ Qb,
    const float* __restrict__ Kw, const float* __restrict__ Kb,
    const float* __restrict__ Vw, const float* __restrict__ Vb,
    _Float16* __restrict__ h16, _Float16* __restrict__ W16,
    float* __restrict__ b_all, int* __restrict__ cursor)
{
    const int bid = blockIdx.x;
    const int t   = threadIdx.x;

    if (bid < CB) {                                    // h -> fp16, 8 floats/thread
        const size_t i = (size_t)bid * 256 + t;
        const float4* hp = (const float4*)hmat;
        float4 x = hp[i * 2];
        float4 y = hp[i * 2 + 1];
        half8 o;
        o[0] = (_Float16)x.x; o[1] = (_Float16)x.y;
        o[2] = (_Float16)x.z; o[3] = (_Float16)x.w;
        o[4] = (_Float16)y.x; o[5] = (_Float16)y.y;
        o[6] = (_Float16)y.z; o[7] = (_Float16)y.w;
        *(half8*)(h16 + i * 8) = o;
        return;
    }
    // last block: W16 = [Kw | Vw | sum_h Qw] fp16, b_all fp32, bucket cursors
    for (int i = t; i < NOUT * IND; i += 256) {
        int r = i >> 7, c = i & 127;
        float v;
        if (r < 128)       v = Kw[i];
        else if (r < 256)  v = Vw[i - 128 * IND];
        else {
            v = 0.f;
#pragma unroll
            for (int hh = 0; hh < NH; hh++) v += Qw[((hh << 4) + (r - 256)) * IND + c];
        }
        W16[i] = (_Float16)v;
    }
    for (int i = t; i < NOUT; i += 256) {
        float v;
        if (i < 128)      v = Kb[i];
        else if (i < 256) v = Vb[i - 128];
        else {
            v = 0.f;
#pragma unroll
            for (int hh = 0; hh < NH; hh++) v += Qb[(hh << 4) + (i - 256)];
        }
        b_all[i] = v;
    }
    for (int i = t; i < NBUCK; i += 256) cursor[i] = i * BCAP;
}

// ---------------- K2: bucket scatter (rank-capture, 1 LDS pass) + MFMA proj ---
// Blocks [0,P1B): 2048 edges each; rank = atomicAdd return; one cursor
// reservation per touched bucket; direct global write (L2 merges lines).
// Blocks [P1B,..): MFMA projection [50000x128]@[128x272].
// A: lane l holds A[m=l&15][k=(l>>4)*8+j]; C/D: col=l&15, row=(l>>4)*4+reg.
__global__ __launch_bounds__(256) void k2_scatter_proj(
    const int* __restrict__ src, const int* __restrict__ dst,
    int* __restrict__ cursor, unsigned int* __restrict__ ebuck,
    const _Float16* __restrict__ h16, const _Float16* __restrict__ W16,
    const float* __restrict__ b_all,
    __half* __restrict__ KVbuf, _Float16* __restrict__ Qs16)
{
    const int t = threadIdx.x;

    if (blockIdx.x < P1B) {
        __shared__ int bcnt[NBUCK];
        __shared__ int baseg[NBUCK];
        for (int i = t; i < NBUCK; i += 256) bcnt[i] = 0;
        __syncthreads();

        const int e0 = blockIdx.x * 2048;
        const int ne = min(2048, NEDGE - e0);
        unsigned int ev[8]; int rk[8];
#pragma unroll
        for (int j = 0; j < 8; j++) {
            int idx = j * 256 + t;
            if (idx < ne) {
                int s = src[e0 + idx], d = dst[e0 + idx];
                unsigned int b = (unsigned int)d >> 6;
                ev[j] = (b << 22) | ((unsigned int)s << 6) | ((unsigned int)d & 63u);
                rk[j] = atomicAdd(&bcnt[b], 1);
            }
        }
        __syncthreads();
        for (int i = t; i < NBUCK; i += 256)
            if (bcnt[i]) baseg[i] = atomicAdd(&cursor[i], bcnt[i]);
        __syncthreads();
#pragma unroll
        for (int j = 0; j < 8; j++) {
            int idx = j * 256 + t;
            if (idx < ne) ebuck[baseg[ev[j] >> 22] + rk[j]] = ev[j];
        }
        return;
    }

    // MFMA projection
    const int pbid = blockIdx.x - P1B;
    const int wave = t >> 6;
    const int l    = t & 63;
    const int cl   = l & 15;
    const int quad = l >> 4;
    const int m0   = pbid * 64 + wave * 16;

    const _Float16* ab = h16 + (size_t)(m0 + cl) * IND + quad * 8;
    half8 afrag[4];
#pragma unroll
    for (int ks = 0; ks < 4; ks++) afrag[ks] = *(const half8*)(ab + ks * 32);

    const int rowbase = m0 + quad * 4;

#pragma unroll 4
    for (int ti = 0; ti < 17; ti++) {
        const _Float16* wb = W16 + (size_t)(ti * 16 + cl) * IND + quad * 8;
        floatx4 acc = {0.f, 0.f, 0.f, 0.f};
#pragma unroll
        for (int ks = 0; ks < 4; ks++)
            acc = __builtin_amdgcn_mfma_f32_16x16x32_f16(
                afrag[ks], *(const half8*)(wb + ks * 32), acc, 0, 0, 0);

        const float bias = b_all[ti * 16 + cl];
        if (ti < 16) {
            const int col = ti * 16 + cl;
#pragma unroll
            for (int r = 0; r < 4; r++) {
                int node = rowbase + r;
                if (node < NNODES)
                    KVbuf[(size_t)node * 256 + col] = __float2half_rn(acc[r] + bias);
            }
        } else {
#pragma unroll
            for (int r = 0; r < 4; r++) {
                int node = rowbase + r;
                if (node < NNODES)
                    Qs16[(size_t)node * OD + cl] = (_Float16)(acc[r] + bias);
            }
        }
    }
}

// ---------------- K3: per-bucket (64 nodes) grouping -> offs/count/eidx16 -----
__global__ __launch_bounds__(256) void k3_group(
    const unsigned int* __restrict__ ebuck, const int* __restrict__ cursor,
    int* __restrict__ offs, int* __restrict__ count,
    unsigned short* __restrict__ eidx16)
{
    __shared__ int cnt[64];
    __shared__ int base64[64];
    const int b = blockIdx.x;
    const int t = threadIdx.x;
    const int start = b * BCAP;
    const int end   = cursor[b];

    if (t < 64) cnt[t] = 0;
    __syncthreads();

    unsigned int ev[10]; int rk[10];
#pragma unroll
    for (int j = 0; j < 10; j++) {
        int i = start + j * 256 + t;
        if (i < end) {
            unsigned int v = ebuck[i];
            ev[j] = v;
            rk[j] = atomicAdd(&cnt[v & 63], 1);
        }
    }
    __syncthreads();

    if (t < 64) {                       // single-wave inclusive scan over 64
        int c = cnt[t];
        int v = c;
#pragma unroll
        for (int ofs = 1; ofs < 64; ofs <<= 1) {
            int x = __shfl_up(v, ofs, 64);
            if (t >= ofs) v += x;
        }
        int excl = v - c;
        base64[t] = excl;
        int node = (b << 6) + t;
        if (node < NNODES) { offs[node] = start + excl; count[node] = c; }
    }
    __syncthreads();

#pragma unroll
    for (int j = 0; j < 10; j++) {
        int i = start + j * 256 + t;
        if (i < end)
            eidx16[start + base64[ev[j] & 63] + rk[j]] =
                (unsigned short)((ev[j] >> 6) & 0xFFFFu);
    }
}

// ---------------- K4: gather-reduce, 16 lanes/edge, 8 edges in flight ---------
// Lane l: eg=l>>4 (edge-pair group), lh=l&15. Lane owns K/V halves
// [8lh,8lh+8) = head lh>>1, dims (lh&1)*8..+8. Score: 4 fdot2 (fp16 Qsum)
// + xor{1}; V: perm-pack 2 edges per dim + fdot2 into fp32 accumulators.
// Self-loop = virtual stream element 0. Epilogue: group-sum (xor 16,32),
// normalize, head-mean (xor 2,4,8), lanes 0-1 write 8 floats each.
__global__ __launch_bounds__(256) void k4_gather(
    const uint4* __restrict__ KV4, const uint4* __restrict__ Qs16u4,
    const int* __restrict__ offs, const int* __restrict__ count,
    const unsigned short* __restrict__ eidx16,
    float* __restrict__ out)
{
    const int n = blockIdx.x * 4 + (threadIdx.x >> 6);
    const int l = threadIdx.x & 63;
    if (n >= NNODES) return;

    const int lh = l & 15;
    const int eg = l >> 4;

    const uint4 qh = Qs16u4[n * 2 + (lh & 1)];

    const int off   = offs[n];
    const int total = count[n] + 1;                  // + self-loop

    float acc[8] = {0.f, 0.f, 0.f, 0.f, 0.f, 0.f, 0.f, 0.f};
    float zacc = 0.f;

    for (int base = 0; base < total; base += 64) {
        const int gi = base + l;
        int id = n;                                  // gi==0 -> self-loop
        if (gi > 0) id = (gi < total) ? (int)eidx16[off + gi - 1] : 0;
        const int steps = min(64, total - base);

        int sA = __shfl(id, 2 * eg, 64);
        int sB = __shfl(id, 2 * eg + 1, 64);
        uint4 kA = KV4[(size_t)sA * 32 + lh];
        uint4 vA = KV4[(size_t)sA * 32 + 16 + lh];
        uint4 kB = KV4[(size_t)sB * 32 + lh];
        uint4 vB = KV4[(size_t)sB * 32 + 16 + lh];

        for (int j = 0; j < steps; j += 8) {
            uint4 kA2, vA2, kB2, vB2;
            const bool pre = (j + 8 < steps);
            if (pre) {
                int sA2 = __shfl(id, j + 8 + 2 * eg, 64);
                int sB2 = __shfl(id, j + 9 + 2 * eg, 64);
                kA2 = KV4[(size_t)sA2 * 32 + lh];
                vA2 = KV4[(size_t)sA2 * 32 + 16 + lh];
                kB2 = KV4[(size_t)sB2 * 32 + lh];
                vB2 = KV4[(size_t)sB2 * 32 + 16 + lh];
            }
            float pA = qdot(kA, qh, 0.f);
            float pB = qdot(kB, qh, 0.f);
            pA += __shfl_xor(pA, 1, 64);
            pB += __shfl_xor(pB, 1, 64);
            float scA = __expf(fminf(5.f, fmaxf(-5.f, pA * 0.25f)));
            float scB = __expf(fminf(5.f, fmaxf(-5.f, pB * 0.25f)));
            if (j + 2 * eg     >= steps) scA = 0.f;
            if (j + 2 * eg + 1 >= steps) scB = 0.f;
            zacc += scA + scB;
            h2t sc2; sc2.x = (_Float16)scA; sc2.y = (_Float16)scB;
            vacc8(vA, vB, sc2, acc);
            kA = kA2; vA = vA2; kB = kB2; vB = vB2;
        }
    }

    // combine the 4 edge groups (l bits 4,5)
#pragma unroll
    for (int i = 0; i < 8; i++) {
        acc[i] += __shfl_xor(acc[i], 16, 64);
        acc[i] += __shfl_xor(acc[i], 32, 64);
    }
    zacc += __shfl_xor(zacc, 16, 64);
    zacc += __shfl_xor(zacc, 32, 64);

    const float inv = 1.f / zacc;                    // z of head lh>>1
    float r[8];
#pragma unroll
    for (int i = 0; i < 8; i++) r[i] = acc[i] * inv;
    // mean over heads: head index = l bits 1..3
#pragma unroll
    for (int i = 0; i < 8; i++) {
        r[i] += __shfl_xor(r[i], 2, 64);
        r[i] += __shfl_xor(r[i], 4, 64);
        r[i] += __shfl_xor(r[i], 8, 64);
    }
    if (l < 2) {
        float4* op = (float4*)(out + (size_t)n * OD + l * 8);
        op[0] = make_float4(r[0] * 0.125f, r[1] * 0.125f, r[2] * 0.125f, r[3] * 0.125f);
        op[1] = make_float4(r[4] * 0.125f, r[5] * 0.125f, r[6] * 0.125f, r[7] * 0.125f);
    }
}

// ---------------- launch ------------------------------------------------------
extern "C" void kernel_launch(void* const* d_in, const int* in_sizes, int n_in,
                              void* d_out, int out_size, void* d_ws, size_t ws_size,
                              hipStream_t stream)
{
    const float* h  = (const float*)d_in[0];
    const float* Qw = (const float*)d_in[1];
    const float* Qb = (const float*)d_in[2];
    const float* Kw = (const float*)d_in[3];
    const float* Kb = (const float*)d_in[4];
    const float* Vw = (const float*)d_in[5];
    const float* Vb = (const float*)d_in[6];
    const int*   src = (const int*)d_in[7];
    const int*   dst = (const int*)d_in[8];

    char* ws = (char*)d_ws;
    _Float16* h16   = (_Float16*)ws;                   ws += (size_t)50048 * IND * 2;
    _Float16* W16   = (_Float16*)ws;                   ws += (size_t)NOUT * IND * 2;
    float*    b_all = (float*)ws;                      ws += 288 * 4;
    __half*   KVbuf = (__half*)ws;                     ws += (size_t)NNODES * 256 * 2;
    _Float16* Qs16  = (_Float16*)ws;                   ws += (size_t)NNODES * OD * 2;
    int*      offs   = (int*)ws;                       ws += (size_t)NNODES * 4;
    int*      count  = (int*)ws;                       ws += (size_t)NNODES * 4;
    int*      cursor = (int*)ws;                       ws += 1024 * 4;
    unsigned int*   ebuck  = (unsigned int*)ws;        ws += (size_t)NBUCK * BCAP * 4;
    unsigned short* eidx16 = (unsigned short*)ws;      ws += (size_t)NBUCK * BCAP * 2;

    k1_conv<<<CB + 1, 256, 0, stream>>>(
        h, Qw, Qb, Kw, Kb, Vw, Vb, h16, W16, b_all, cursor);

    k2_scatter_proj<<<P1B + PB2, 256, 0, stream>>>(
        src, dst, cursor, ebuck, h16, W16, b_all, KVbuf, Qs16);

    k3_group<<<NBUCK, 256, 0, stream>>>(ebuck, cursor, offs, count, eidx16);

    k4_gather<<<(NNODES + 3) / 4, 256, 0, stream>>>(
        (const uint4*)KVbuf, (const uint4*)Qs16, offs, count, eidx16, (float*)d_out);
}

// Round 9
// 279.871 us; speedup vs baseline: 1.7440x; 1.0664x over previous
//
#include <hip/hip_runtime.h>
#include <hip/hip_fp16.h>
#include <math.h>

#define NNODES 50000
#define IND    128
#define NH     8
#define OD     16
#define NEDGE  1600000
#define NOUT   272           // 128 K + 128 V + 16 Qsum
#define NBUCK  391           // dst>>7 buckets (128 nodes each)
#define BCAP   4608          // per-bucket capacity (mean 4096, +8 sigma); 18*256
#define P1B    196           // edge chunks of 8192
#define CB     3125          // h->fp16 convert blocks
#define PB2    782           // ceil(50000/64) MFMA-proj blocks

typedef _Float16 half8 __attribute__((ext_vector_type(8)));
typedef _Float16 h2t   __attribute__((ext_vector_type(2)));
typedef float    floatx4 __attribute__((ext_vector_type(4)));

static __device__ __forceinline__ h2t u2h(unsigned int u) {
    union { unsigned int u; h2t h; } x; x.u = u; return x.h;
}
static __device__ __forceinline__ float qdot(uint4 k, uint4 q, float p) {
    p = __builtin_amdgcn_fdot2(u2h(k.x), u2h(q.x), p, false);
    p = __builtin_amdgcn_fdot2(u2h(k.y), u2h(q.y), p, false);
    p = __builtin_amdgcn_fdot2(u2h(k.z), u2h(q.z), p, false);
    p = __builtin_amdgcn_fdot2(u2h(k.w), u2h(q.w), p, false);
    return p;
}
// acc[d] += vA[d]*scA + vB[d]*scB for 8 dims, fp32 accumulators.
static __device__ __forceinline__ void vacc8(uint4 vA, uint4 vB, h2t sc2, float* acc) {
    unsigned lo, hi;
    lo = __builtin_amdgcn_perm(vB.x, vA.x, 0x05040100u);
    hi = __builtin_amdgcn_perm(vB.x, vA.x, 0x07060302u);
    acc[0] = __builtin_amdgcn_fdot2(u2h(lo), sc2, acc[0], false);
    acc[1] = __builtin_amdgcn_fdot2(u2h(hi), sc2, acc[1], false);
    lo = __builtin_amdgcn_perm(vB.y, vA.y, 0x05040100u);
    hi = __builtin_amdgcn_perm(vB.y, vA.y, 0x07060302u);
    acc[2] = __builtin_amdgcn_fdot2(u2h(lo), sc2, acc[2], false);
    acc[3] = __builtin_amdgcn_fdot2(u2h(hi), sc2, acc[3], false);
    lo = __builtin_amdgcn_perm(vB.z, vA.z, 0x05040100u);
    hi = __builtin_amdgcn_perm(vB.z, vA.z, 0x07060302u);
    acc[4] = __builtin_amdgcn_fdot2(u2h(lo), sc2, acc[4], false);
    acc[5] = __builtin_amdgcn_fdot2(u2h(hi), sc2, acc[5], false);
    lo = __builtin_amdgcn_perm(vB.w, vA.w, 0x05040100u);
    hi = __builtin_amdgcn_perm(vB.w, vA.w, 0x07060302u);
    acc[6] = __builtin_amdgcn_fdot2(u2h(lo), sc2, acc[6], false);
    acc[7] = __builtin_amdgcn_fdot2(u2h(hi), sc2, acc[7], false);
}

// ---------------- K1: h->fp16 convert + W16/b_all build + cursor init ---------
__global__ __launch_bounds__(256) void k1_conv(
    const float* __restrict__ hmat,
    const float* __restrict__ Qw, const float* __restrict__ Qb,
    const float* __restrict__ Kw, const float* __restrict__ Kb,
    const float* __restrict__ Vw, const float* __restrict__ Vb,
    _Float16* __restrict__ h16, _Float16* __restrict__ W16,
    float* __restrict__ b_all, int* __restrict__ cursor)
{
    const int bid = blockIdx.x;
    const int t   = threadIdx.x;

    if (bid < CB) {                                    // h -> fp16, 8 floats/thread
        const size_t i = (size_t)bid * 256 + t;
        const float4* hp = (const float4*)hmat;
        float4 x = hp[i * 2];
        float4 y = hp[i * 2 + 1];
        half8 o;
        o[0] = (_Float16)x.x; o[1] = (_Float16)x.y;
        o[2] = (_Float16)x.z; o[3] = (_Float16)x.w;
        o[4] = (_Float16)y.x; o[5] = (_Float16)y.y;
        o[6] = (_Float16)y.z; o[7] = (_Float16)y.w;
        *(half8*)(h16 + i * 8) = o;
        return;
    }
    // last block: W16 = [Kw | Vw | sum_h Qw] fp16, b_all fp32, bucket cursors
    for (int i = t; i < NOUT * IND; i += 256) {
        int r = i >> 7, c = i & 127;
        float v;
        if (r < 128)       v = Kw[i];
        else if (r < 256)  v = Vw[i - 128 * IND];
        else {
            v = 0.f;
#pragma unroll
            for (int hh = 0; hh < NH; hh++) v += Qw[((hh << 4) + (r - 256)) * IND + c];
        }
        W16[i] = (_Float16)v;
    }
    for (int i = t; i < NOUT; i += 256) {
        float v;
        if (i < 128)      v = Kb[i];
        else if (i < 256) v = Vb[i - 128];
        else {
            v = 0.f;
#pragma unroll
            for (int hh = 0; hh < NH; hh++) v += Qb[(hh << 4) + (i - 256)];
        }
        b_all[i] = v;
    }
    for (int i = t; i < NBUCK; i += 256) cursor[i] = i * BCAP;
}

// ---------------- K2: bucket scatter (registers + rank capture) + MFMA proj ---
// Blocks [0,P1B): 8192 edges each held in uint4 regs; rank = LDS atomicAdd
// return; one cursor reservation per touched bucket (196x~390 = 76K global
// atomics); bucket runs ~21 edges (line-exclusive-ish). Blocks [P1B,..):
// MFMA projection [50000x128]@[128x272].
// A: lane l holds A[m=l&15][k=(l>>4)*8+j]; C/D: col=l&15, row=(l>>4)*4+reg.
__global__ __launch_bounds__(256) void k2_scatter_proj(
    const int* __restrict__ src, const int* __restrict__ dst,
    int* __restrict__ cursor, unsigned int* __restrict__ ebuck,
    const _Float16* __restrict__ h16, const _Float16* __restrict__ W16,
    const float* __restrict__ b_all,
    __half* __restrict__ KVbuf, _Float16* __restrict__ Qs16)
{
    const int t = threadIdx.x;

    if (blockIdx.x < P1B) {
        __shared__ int bcnt[NBUCK];
        __shared__ int baseg[NBUCK];
        for (int i = t; i < NBUCK; i += 256) bcnt[i] = 0;
        __syncthreads();

        const int e0 = blockIdx.x * 8192;
        const int nq = (min(8192, NEDGE - e0)) >> 2;   // quads (tail is mult of 4)
        const int4* s4 = (const int4*)(src + e0);
        const int4* d4 = (const int4*)(dst + e0);

        uint4 ev4[8];
        unsigned int rkp[16];                          // 32 ranks, 2x16b per int
#pragma unroll
        for (int j = 0; j < 8; j++) {
            int qi = j * 256 + t;
            if (qi < nq) {
                int4 ss = s4[qi];
                int4 dd = d4[qi];
                unsigned int v0 = (((unsigned)dd.x >> 7) << 23) | ((unsigned)ss.x << 7) | ((unsigned)dd.x & 127u);
                unsigned int v1 = (((unsigned)dd.y >> 7) << 23) | ((unsigned)ss.y << 7) | ((unsigned)dd.y & 127u);
                unsigned int v2 = (((unsigned)dd.z >> 7) << 23) | ((unsigned)ss.z << 7) | ((unsigned)dd.z & 127u);
                unsigned int v3 = (((unsigned)dd.w >> 7) << 23) | ((unsigned)ss.w << 7) | ((unsigned)dd.w & 127u);
                ev4[j] = make_uint4(v0, v1, v2, v3);
                unsigned r0 = atomicAdd(&bcnt[v0 >> 23], 1);
                unsigned r1 = atomicAdd(&bcnt[v1 >> 23], 1);
                unsigned r2 = atomicAdd(&bcnt[v2 >> 23], 1);
                unsigned r3 = atomicAdd(&bcnt[v3 >> 23], 1);
                rkp[2 * j]     = r0 | (r1 << 16);
                rkp[2 * j + 1] = r2 | (r3 << 16);
            }
        }
        __syncthreads();
        for (int i = t; i < NBUCK; i += 256)
            if (bcnt[i]) baseg[i] = atomicAdd(&cursor[i], bcnt[i]);
        __syncthreads();
#pragma unroll
        for (int j = 0; j < 8; j++) {
            int qi = j * 256 + t;
            if (qi < nq) {
                uint4 v = ev4[j];
                unsigned p0 = rkp[2 * j], p1 = rkp[2 * j + 1];
                ebuck[baseg[v.x >> 23] + (p0 & 0xFFFFu)] = v.x;
                ebuck[baseg[v.y >> 23] + (p0 >> 16)]     = v.y;
                ebuck[baseg[v.z >> 23] + (p1 & 0xFFFFu)] = v.z;
                ebuck[baseg[v.w >> 23] + (p1 >> 16)]     = v.w;
            }
        }
        return;
    }

    // MFMA projection
    const int pbid = blockIdx.x - P1B;
    const int wave = t >> 6;
    const int l    = t & 63;
    const int cl   = l & 15;
    const int quad = l >> 4;
    const int m0   = pbid * 64 + wave * 16;

    const _Float16* ab = h16 + (size_t)(m0 + cl) * IND + quad * 8;
    half8 afrag[4];
#pragma unroll
    for (int ks = 0; ks < 4; ks++) afrag[ks] = *(const half8*)(ab + ks * 32);

    const int rowbase = m0 + quad * 4;

#pragma unroll 4
    for (int ti = 0; ti < 17; ti++) {
        const _Float16* wb = W16 + (size_t)(ti * 16 + cl) * IND + quad * 8;
        floatx4 acc = {0.f, 0.f, 0.f, 0.f};
#pragma unroll
        for (int ks = 0; ks < 4; ks++)
            acc = __builtin_amdgcn_mfma_f32_16x16x32_f16(
                afrag[ks], *(const half8*)(wb + ks * 32), acc, 0, 0, 0);

        const float bias = b_all[ti * 16 + cl];
        if (ti < 16) {
            const int col = ti * 16 + cl;
#pragma unroll
            for (int r = 0; r < 4; r++) {
                int node = rowbase + r;
                if (node < NNODES)
                    KVbuf[(size_t)node * 256 + col] = __float2half_rn(acc[r] + bias);
            }
        } else {
#pragma unroll
            for (int r = 0; r < 4; r++) {
                int node = rowbase + r;
                if (node < NNODES)
                    Qs16[(size_t)node * OD + cl] = (_Float16)(acc[r] + bias);
            }
        }
    }
}

// ---------------- K3: per-bucket (128 nodes) grouping -> offs/count/eidx16 ----
__global__ __launch_bounds__(256) void k3_group(
    const unsigned int* __restrict__ ebuck, const int* __restrict__ cursor,
    int* __restrict__ offs, int* __restrict__ count,
    unsigned short* __restrict__ eidx16)
{
    __shared__ int cnt[128];
    __shared__ int base128[128];
    const int b = blockIdx.x;
    const int t = threadIdx.x;
    const int start = b * BCAP;
    const int end   = cursor[b];

    if (t < 128) cnt[t] = 0;
    __syncthreads();

    int rk[18];
#pragma unroll
    for (int j = 0; j < 18; j++) {
        int i = start + j * 256 + t;
        if (i < end) rk[j] = atomicAdd(&cnt[ebuck[i] & 127], 1);
    }
    __syncthreads();

    // Hillis-Steele inclusive scan over 128 counters
    int c = 0, v = 0;
    if (t < 128) { c = cnt[t]; v = c; }
    for (int ofs = 1; ofs < 128; ofs <<= 1) {
        int x = (t >= ofs && t < 128) ? base128[0] : 0;  // placeholder to keep syncs balanced
        (void)x;
        __syncthreads();
        if (t < 128) base128[t] = v;
        __syncthreads();
        if (t >= ofs && t < 128) v += base128[t - ofs];
    }
    __syncthreads();
    if (t < 128) {
        int excl = v - c;
        base128[t] = excl;
        int node = (b << 7) + t;
        if (node < NNODES) { offs[node] = start + excl; count[node] = c; }
    }
    __syncthreads();

#pragma unroll
    for (int j = 0; j < 18; j++) {
        int i = start + j * 256 + t;
        if (i < end) {
            unsigned int e = ebuck[i];
            eidx16[start + base128[e & 127] + rk[j]] =
                (unsigned short)((e >> 7) & 0xFFFFu);
        }
    }
}

// ---------------- K4: gather-reduce, 16 lanes/edge, 2-deep prefetch -----------
// Lane l: eg=l>>4, lh=l&15. Lane owns K/V halves [8lh,8lh+8) = head lh>>1,
// dims (lh&1)*8..+8. Score: 4 fdot2 + xor{1}; V: perm-pack 2 edges + fdot2
// into fp32 accumulators. 3-stage load rotation = 8 outstanding loads/wave.
__global__ __launch_bounds__(256) void k4_gather(
    const uint4* __restrict__ KV4, const uint4* __restrict__ Qs16u4,
    const int* __restrict__ offs, const int* __restrict__ count,
    const unsigned short* __restrict__ eidx16,
    float* __restrict__ out)
{
    const int n = blockIdx.x * 4 + (threadIdx.x >> 6);
    const int l = threadIdx.x & 63;
    if (n >= NNODES) return;

    const int lh = l & 15;
    const int eg = l >> 4;
    const int la = 2 * eg, lb = 2 * eg + 1;

    const uint4 qh = Qs16u4[n * 2 + (lh & 1)];

    const int off   = offs[n];
    const int total = count[n] + 1;                  // + self-loop

    float acc[8] = {0.f, 0.f, 0.f, 0.f, 0.f, 0.f, 0.f, 0.f};
    float zacc = 0.f;

    for (int base = 0; base < total; base += 64) {
        const int gi = base + l;
        int id = n;                                  // gi==0 -> self-loop
        if (gi > 0) id = (gi < total) ? (int)eidx16[off + gi - 1] : 0;
        const int steps = min(64, total - base);

        // stage 0
        int sA = __shfl(id, la, 64), sB = __shfl(id, lb, 64);
        uint4 kA0 = KV4[(size_t)sA * 32 + lh];
        uint4 vA0 = KV4[(size_t)sA * 32 + 16 + lh];
        uint4 kB0 = KV4[(size_t)sB * 32 + lh];
        uint4 vB0 = KV4[(size_t)sB * 32 + 16 + lh];
        // stage 1
        int n1a = 8 + la, n1b = 8 + lb;
        int sA1 = __shfl(id, (n1a < 64) ? n1a : 0, 64);
        int sB1 = __shfl(id, (n1b < 64) ? n1b : 0, 64);
        uint4 kA1 = KV4[(size_t)sA1 * 32 + lh];
        uint4 vA1 = KV4[(size_t)sA1 * 32 + 16 + lh];
        uint4 kB1 = KV4[(size_t)sB1 * 32 + lh];
        uint4 vB1 = KV4[(size_t)sB1 * 32 + 16 + lh];

        for (int j = 0; j < steps; j += 8) {
            uint4 kA2, vA2, kB2, vB2;
            if (j + 16 < steps) {                    // prefetch stage j+16
                int n2a = j + 16 + la, n2b = j + 16 + lb;
                int sA2 = __shfl(id, (n2a < 64) ? n2a : 0, 64);
                int sB2 = __shfl(id, (n2b < 64) ? n2b : 0, 64);
                kA2 = KV4[(size_t)sA2 * 32 + lh];
                vA2 = KV4[(size_t)sA2 * 32 + 16 + lh];
                kB2 = KV4[(size_t)sB2 * 32 + lh];
                vB2 = KV4[(size_t)sB2 * 32 + 16 + lh];
            }
            float pA = qdot(kA0, qh, 0.f);
            float pB = qdot(kB0, qh, 0.f);
            pA += __shfl_xor(pA, 1, 64);
            pB += __shfl_xor(pB, 1, 64);
            float scA = __expf(fminf(5.f, fmaxf(-5.f, pA * 0.25f)));
            float scB = __expf(fminf(5.f, fmaxf(-5.f, pB * 0.25f)));
            if (j + la >= steps) scA = 0.f;
            if (j + lb >= steps) scB = 0.f;
            zacc += scA + scB;
            h2t sc2; sc2.x = (_Float16)scA; sc2.y = (_Float16)scB;
            vacc8(vA0, vB0, sc2, acc);
            kA0 = kA1; vA0 = vA1; kB0 = kB1; vB0 = vB1;
            kA1 = kA2; vA1 = vA2; kB1 = kB2; vB1 = vB2;
        }
    }

    // combine the 4 edge groups (l bits 4,5)
#pragma unroll
    for (int i = 0; i < 8; i++) {
        acc[i] += __shfl_xor(acc[i], 16, 64);
        acc[i] += __shfl_xor(acc[i], 32, 64);
    }
    zacc += __shfl_xor(zacc, 16, 64);
    zacc += __shfl_xor(zacc, 32, 64);

    const float inv = 1.f / zacc;                    // z of head lh>>1
    float r[8];
#pragma unroll
    for (int i = 0; i < 8; i++) r[i] = acc[i] * inv;
    // mean over heads: head index = l bits 1..3
#pragma unroll
    for (int i = 0; i < 8; i++) {
        r[i] += __shfl_xor(r[i], 2, 64);
        r[i] += __shfl_xor(r[i], 4, 64);
        r[i] += __shfl_xor(r[i], 8, 64);
    }
    if (l < 2) {
        float4* op = (float4*)(out + (size_t)n * OD + l * 8);
        op[0] = make_float4(r[0] * 0.125f, r[1] * 0.125f, r[2] * 0.125f, r[3] * 0.125f);
        op[1] = make_float4(r[4] * 0.125f, r[5] * 0.125f, r[6] * 0.125f, r[7] * 0.125f);
    }
}

// ---------------- launch ------------------------------------------------------
extern "C" void kernel_launch(void* const* d_in, const int* in_sizes, int n_in,
                              void* d_out, int out_size, void* d_ws, size_t ws_size,
                              hipStream_t stream)
{
    const float* h  = (const float*)d_in[0];
    const float* Qw = (const float*)d_in[1];
    const float* Qb = (const float*)d_in[2];
    const float* Kw = (const float*)d_in[3];
    const float* Kb = (const float*)d_in[4];
    const float* Vw = (const float*)d_in[5];
    const float* Vb = (const float*)d_in[6];
    const int*   src = (const int*)d_in[7];
    const int*   dst = (const int*)d_in[8];

    char* ws = (char*)d_ws;
    _Float16* h16   = (_Float16*)ws;                   ws += (size_t)50048 * IND * 2;
    _Float16* W16   = (_Float16*)ws;                   ws += (size_t)NOUT * IND * 2;
    float*    b_all = (float*)ws;                      ws += 288 * 4;
    __half*   KVbuf = (__half*)ws;                     ws += (size_t)NNODES * 256 * 2;
    _Float16* Qs16  = (_Float16*)ws;                   ws += (size_t)NNODES * OD * 2;
    int*      offs   = (int*)ws;                       ws += (size_t)NNODES * 4;
    int*      count  = (int*)ws;                       ws += (size_t)NNODES * 4;
    int*      cursor = (int*)ws;                       ws += 1024 * 4;
    unsigned int*   ebuck  = (unsigned int*)ws;        ws += (size_t)NBUCK * BCAP * 4;
    unsigned short* eidx16 = (unsigned short*)ws;      ws += (size_t)NBUCK * BCAP * 2;

    k1_conv<<<CB + 1, 256, 0, stream>>>(
        h, Qw, Qb, Kw, Kb, Vw, Vb, h16, W16, b_all, cursor);

    k2_scatter_proj<<<P1B + PB2, 256, 0, stream>>>(
        src, dst, cursor, ebuck, h16, W16, b_all, KVbuf, Qs16);

    k3_group<<<NBUCK, 256, 0, stream>>>(ebuck, cursor, offs, count, eidx16);

    k4_gather<<<(NNODES + 3) / 4, 256, 0, stream>>>(
        (const uint4*)KVbuf, (const uint4*)Qs16, offs, count, eidx16, (float*)d_out);
}

// Round 10
// 270.204 us; speedup vs baseline: 1.8064x; 1.0358x over previous
//
#include <hip/hip_runtime.h>
#include <hip/hip_fp16.h>
#include <math.h>

#define NNODES 50000
#define IND    128
#define NH     8
#define OD     16
#define NEDGE  1600000
#define NOUT   272           // 128 K + 128 V + 16 Qsum
#define NBUCK  391           // dst>>7 buckets (128 nodes each)
#define BCAP   4608          // per-bucket capacity (mean 4096, +8 sigma); 18*256
#define P1B    196           // edge chunks of 8192
#define PB2    782           // ceil(50000/64) MFMA-proj blocks

typedef _Float16 half8 __attribute__((ext_vector_type(8)));
typedef _Float16 h2t   __attribute__((ext_vector_type(2)));
typedef float    floatx4 __attribute__((ext_vector_type(4)));

static __device__ __forceinline__ h2t u2h(unsigned int u) {
    union { unsigned int u; h2t h; } x; x.u = u; return x.h;
}
static __device__ __forceinline__ float qdot(uint4 k, uint4 q, float p) {
    p = __builtin_amdgcn_fdot2(u2h(k.x), u2h(q.x), p, false);
    p = __builtin_amdgcn_fdot2(u2h(k.y), u2h(q.y), p, false);
    p = __builtin_amdgcn_fdot2(u2h(k.z), u2h(q.z), p, false);
    p = __builtin_amdgcn_fdot2(u2h(k.w), u2h(q.w), p, false);
    return p;
}
// acc[d] += vA[d]*scA + vB[d]*scB for 8 dims, fp32 accumulators.
static __device__ __forceinline__ void vacc8(uint4 vA, uint4 vB, h2t sc2, float* acc) {
    unsigned lo, hi;
    lo = __builtin_amdgcn_perm(vB.x, vA.x, 0x05040100u);
    hi = __builtin_amdgcn_perm(vB.x, vA.x, 0x07060302u);
    acc[0] = __builtin_amdgcn_fdot2(u2h(lo), sc2, acc[0], false);
    acc[1] = __builtin_amdgcn_fdot2(u2h(hi), sc2, acc[1], false);
    lo = __builtin_amdgcn_perm(vB.y, vA.y, 0x05040100u);
    hi = __builtin_amdgcn_perm(vB.y, vA.y, 0x07060302u);
    acc[2] = __builtin_amdgcn_fdot2(u2h(lo), sc2, acc[2], false);
    acc[3] = __builtin_amdgcn_fdot2(u2h(hi), sc2, acc[3], false);
    lo = __builtin_amdgcn_perm(vB.z, vA.z, 0x05040100u);
    hi = __builtin_amdgcn_perm(vB.z, vA.z, 0x07060302u);
    acc[4] = __builtin_amdgcn_fdot2(u2h(lo), sc2, acc[4], false);
    acc[5] = __builtin_amdgcn_fdot2(u2h(hi), sc2, acc[5], false);
    lo = __builtin_amdgcn_perm(vB.w, vA.w, 0x05040100u);
    hi = __builtin_amdgcn_perm(vB.w, vA.w, 0x07060302u);
    acc[6] = __builtin_amdgcn_fdot2(u2h(lo), sc2, acc[6], false);
    acc[7] = __builtin_amdgcn_fdot2(u2h(hi), sc2, acc[7], false);
}

// ---------------- KA: bucket scatter (rank capture) + W16/b_all build ---------
// Blocks [0,P1B): 8192 edges in uint4 regs; rank = LDS atomicAdd return; one
// global reservation per touched bucket. bcount is a zeroed COUNT (memset),
// slot = b*BCAP + reserved. Last block: W16 = [Kw | Vw | sum_h Qw] fp16.
__global__ __launch_bounds__(256) void ka_scatter_w16(
    const int* __restrict__ src, const int* __restrict__ dst,
    int* __restrict__ bcount, unsigned int* __restrict__ ebuck,
    const float* __restrict__ Qw, const float* __restrict__ Qb,
    const float* __restrict__ Kw, const float* __restrict__ Kb,
    const float* __restrict__ Vw, const float* __restrict__ Vb,
    _Float16* __restrict__ W16, float* __restrict__ b_all)
{
    const int t = threadIdx.x;

    if (blockIdx.x < P1B) {
        __shared__ int bcnt[NBUCK];
        __shared__ int baseg[NBUCK];
        for (int i = t; i < NBUCK; i += 256) bcnt[i] = 0;
        __syncthreads();

        const int e0 = blockIdx.x * 8192;
        const int nq = (min(8192, NEDGE - e0)) >> 2;   // quads
        const int4* s4 = (const int4*)(src + e0);
        const int4* d4 = (const int4*)(dst + e0);

        uint4 ev4[8];
        unsigned int rkp[16];
#pragma unroll
        for (int j = 0; j < 8; j++) {
            int qi = j * 256 + t;
            if (qi < nq) {
                int4 ss = s4[qi];
                int4 dd = d4[qi];
                unsigned int v0 = (((unsigned)dd.x >> 7) << 23) | ((unsigned)ss.x << 7) | ((unsigned)dd.x & 127u);
                unsigned int v1 = (((unsigned)dd.y >> 7) << 23) | ((unsigned)ss.y << 7) | ((unsigned)dd.y & 127u);
                unsigned int v2 = (((unsigned)dd.z >> 7) << 23) | ((unsigned)ss.z << 7) | ((unsigned)dd.z & 127u);
                unsigned int v3 = (((unsigned)dd.w >> 7) << 23) | ((unsigned)ss.w << 7) | ((unsigned)dd.w & 127u);
                ev4[j] = make_uint4(v0, v1, v2, v3);
                unsigned r0 = atomicAdd(&bcnt[v0 >> 23], 1);
                unsigned r1 = atomicAdd(&bcnt[v1 >> 23], 1);
                unsigned r2 = atomicAdd(&bcnt[v2 >> 23], 1);
                unsigned r3 = atomicAdd(&bcnt[v3 >> 23], 1);
                rkp[2 * j]     = r0 | (r1 << 16);
                rkp[2 * j + 1] = r2 | (r3 << 16);
            }
        }
        __syncthreads();
        for (int i = t; i < NBUCK; i += 256)
            if (bcnt[i]) baseg[i] = i * BCAP + atomicAdd(&bcount[i], bcnt[i]);
        __syncthreads();
#pragma unroll
        for (int j = 0; j < 8; j++) {
            int qi = j * 256 + t;
            if (qi < nq) {
                uint4 v = ev4[j];
                unsigned p0 = rkp[2 * j], p1 = rkp[2 * j + 1];
                ebuck[baseg[v.x >> 23] + (p0 & 0xFFFFu)] = v.x;
                ebuck[baseg[v.y >> 23] + (p0 >> 16)]     = v.y;
                ebuck[baseg[v.z >> 23] + (p1 & 0xFFFFu)] = v.z;
                ebuck[baseg[v.w >> 23] + (p1 >> 16)]     = v.w;
            }
        }
        return;
    }

    // W16 = [Kw | Vw | sum_h Qw] fp16, b_all fp32
    for (int i = t; i < NOUT * IND; i += 256) {
        int r = i >> 7, c = i & 127;
        float v;
        if (r < 128)       v = Kw[i];
        else if (r < 256)  v = Vw[i - 128 * IND];
        else {
            v = 0.f;
#pragma unroll
            for (int hh = 0; hh < NH; hh++) v += Qw[((hh << 4) + (r - 256)) * IND + c];
        }
        W16[i] = (_Float16)v;
    }
    for (int i = t; i < NOUT; i += 256) {
        float v;
        if (i < 128)      v = Kb[i];
        else if (i < 256) v = Vb[i - 128];
        else {
            v = 0.f;
#pragma unroll
            for (int hh = 0; hh < NH; hh++) v += Qb[(hh << 4) + (i - 256)];
        }
        b_all[i] = v;
    }
}

// ---------------- KB: MFMA proj (fp32 h, in-reg cvt) + per-bucket grouping ----
// Blocks [0,PB2): projection [50000x128]@[128x272]; A-frags converted from
// fp32 h in registers (no h16 buffer). A: lane l holds A[m=l&15][k=(l>>4)*8+j];
// C/D: col=l&15, row=(l>>4)*4+reg. Blocks [PB2,PB2+NBUCK): group each
// 128-node bucket -> offs/count/eidx16.
__global__ __launch_bounds__(256) void kb_proj_group(
    const float* __restrict__ hmat,
    const _Float16* __restrict__ W16, const float* __restrict__ b_all,
    __half* __restrict__ KVbuf, _Float16* __restrict__ Qs16,
    const unsigned int* __restrict__ ebuck, const int* __restrict__ bcount,
    int* __restrict__ offs, int* __restrict__ count,
    unsigned short* __restrict__ eidx16)
{
    const int t = threadIdx.x;

    if (blockIdx.x < PB2) {                            // projection
        const int wave = t >> 6;
        const int l    = t & 63;
        const int cl   = l & 15;
        const int quad = l >> 4;
        const int m0   = blockIdx.x * 64 + wave * 16;

        const int arow = min(m0 + cl, NNODES - 1);     // clamp OOB tail rows
        const float* ab = hmat + (size_t)arow * IND + quad * 8;
        half8 afrag[4];
#pragma unroll
        for (int ks = 0; ks < 4; ks++) {
            float4 x = *(const float4*)(ab + ks * 32);
            float4 y = *(const float4*)(ab + ks * 32 + 4);
            half8 o;
            o[0] = (_Float16)x.x; o[1] = (_Float16)x.y;
            o[2] = (_Float16)x.z; o[3] = (_Float16)x.w;
            o[4] = (_Float16)y.x; o[5] = (_Float16)y.y;
            o[6] = (_Float16)y.z; o[7] = (_Float16)y.w;
            afrag[ks] = o;
        }

        const int rowbase = m0 + quad * 4;

#pragma unroll 4
        for (int ti = 0; ti < 17; ti++) {
            const _Float16* wb = W16 + (size_t)(ti * 16 + cl) * IND + quad * 8;
            floatx4 acc = {0.f, 0.f, 0.f, 0.f};
#pragma unroll
            for (int ks = 0; ks < 4; ks++)
                acc = __builtin_amdgcn_mfma_f32_16x16x32_f16(
                    afrag[ks], *(const half8*)(wb + ks * 32), acc, 0, 0, 0);

            const float bias = b_all[ti * 16 + cl];
            if (ti < 16) {
                const int col = ti * 16 + cl;
#pragma unroll
                for (int r = 0; r < 4; r++) {
                    int node = rowbase + r;
                    if (node < NNODES)
                        KVbuf[(size_t)node * 256 + col] = __float2half_rn(acc[r] + bias);
                }
            } else {
#pragma unroll
                for (int r = 0; r < 4; r++) {
                    int node = rowbase + r;
                    if (node < NNODES)
                        Qs16[(size_t)node * OD + cl] = (_Float16)(acc[r] + bias);
                }
            }
        }
        return;
    }

    // grouping
    __shared__ int cnt[128];
    __shared__ int sd[128];
    __shared__ int base128[128];
    const int b = blockIdx.x - PB2;
    const int start = b * BCAP;
    const int end   = start + bcount[b];

    if (t < 128) cnt[t] = 0;
    __syncthreads();

    int rk[18];
#pragma unroll
    for (int j = 0; j < 18; j++) {
        int i = start + j * 256 + t;
        if (i < end) rk[j] = atomicAdd(&cnt[ebuck[i] & 127], 1);
    }
    __syncthreads();

    if (t < 128) sd[t] = cnt[t];
    __syncthreads();
    for (int ofs = 1; ofs < 128; ofs <<= 1) {
        int x = 0;
        if (t < 128 && t >= ofs) x = sd[t - ofs];
        __syncthreads();
        if (t < 128) sd[t] += x;
        __syncthreads();
    }
    if (t < 128) {
        int excl = sd[t] - cnt[t];
        base128[t] = excl;
        int node = (b << 7) + t;
        if (node < NNODES) { offs[node] = start + excl; count[node] = cnt[t]; }
    }
    __syncthreads();

#pragma unroll
    for (int j = 0; j < 18; j++) {
        int i = start + j * 256 + t;
        if (i < end) {
            unsigned int e = ebuck[i];
            eidx16[start + base128[e & 127] + rk[j]] =
                (unsigned short)((e >> 7) & 0xFFFFu);
        }
    }
}

// ---------------- KC: gather-reduce, 16 lanes/edge, 2-deep prefetch -----------
// Lane l: eg=l>>4, lh=l&15. Lane owns K/V halves [8lh,8lh+8) = head lh>>1,
// dims (lh&1)*8..+8. Score: 4 fdot2 + xor{1}; V: perm-pack 2 edges + fdot2
// into fp32 accumulators. 3-stage load rotation = 8 outstanding loads/wave.
__global__ __launch_bounds__(256) void kc_gather(
    const uint4* __restrict__ KV4, const uint4* __restrict__ Qs16u4,
    const int* __restrict__ offs, const int* __restrict__ count,
    const unsigned short* __restrict__ eidx16,
    float* __restrict__ out)
{
    const int n = blockIdx.x * 4 + (threadIdx.x >> 6);
    const int l = threadIdx.x & 63;
    if (n >= NNODES) return;

    const int lh = l & 15;
    const int eg = l >> 4;
    const int la = 2 * eg, lb = 2 * eg + 1;

    const uint4 qh = Qs16u4[n * 2 + (lh & 1)];

    const int off   = offs[n];
    const int total = count[n] + 1;                  // + self-loop

    float acc[8] = {0.f, 0.f, 0.f, 0.f, 0.f, 0.f, 0.f, 0.f};
    float zacc = 0.f;

    for (int base = 0; base < total; base += 64) {
        const int gi = base + l;
        int id = n;                                  // gi==0 -> self-loop
        if (gi > 0) id = (gi < total) ? (int)eidx16[off + gi - 1] : 0;
        const int steps = min(64, total - base);

        int sA = __shfl(id, la, 64), sB = __shfl(id, lb, 64);
        uint4 kA0 = KV4[(size_t)sA * 32 + lh];
        uint4 vA0 = KV4[(size_t)sA * 32 + 16 + lh];
        uint4 kB0 = KV4[(size_t)sB * 32 + lh];
        uint4 vB0 = KV4[(size_t)sB * 32 + 16 + lh];
        int n1a = 8 + la, n1b = 8 + lb;
        int sA1 = __shfl(id, (n1a < 64) ? n1a : 0, 64);
        int sB1 = __shfl(id, (n1b < 64) ? n1b : 0, 64);
        uint4 kA1 = KV4[(size_t)sA1 * 32 + lh];
        uint4 vA1 = KV4[(size_t)sA1 * 32 + 16 + lh];
        uint4 kB1 = KV4[(size_t)sB1 * 32 + lh];
        uint4 vB1 = KV4[(size_t)sB1 * 32 + 16 + lh];

        for (int j = 0; j < steps; j += 8) {
            uint4 kA2, vA2, kB2, vB2;
            if (j + 16 < steps) {
                int n2a = j + 16 + la, n2b = j + 16 + lb;
                int sA2 = __shfl(id, (n2a < 64) ? n2a : 0, 64);
                int sB2 = __shfl(id, (n2b < 64) ? n2b : 0, 64);
                kA2 = KV4[(size_t)sA2 * 32 + lh];
                vA2 = KV4[(size_t)sA2 * 32 + 16 + lh];
                kB2 = KV4[(size_t)sB2 * 32 + lh];
                vB2 = KV4[(size_t)sB2 * 32 + 16 + lh];
            }
            float pA = qdot(kA0, qh, 0.f);
            float pB = qdot(kB0, qh, 0.f);
            pA += __shfl_xor(pA, 1, 64);
            pB += __shfl_xor(pB, 1, 64);
            float scA = __expf(fminf(5.f, fmaxf(-5.f, pA * 0.25f)));
            float scB = __expf(fminf(5.f, fmaxf(-5.f, pB * 0.25f)));
            if (j + la >= steps) scA = 0.f;
            if (j + lb >= steps) scB = 0.f;
            zacc += scA + scB;
            h2t sc2; sc2.x = (_Float16)scA; sc2.y = (_Float16)scB;
            vacc8(vA0, vB0, sc2, acc);
            kA0 = kA1; vA0 = vA1; kB0 = kB1; vB0 = vB1;
            kA1 = kA2; vA1 = vA2; kB1 = kB2; vB1 = vB2;
        }
    }

    // combine the 4 edge groups (l bits 4,5)
#pragma unroll
    for (int i = 0; i < 8; i++) {
        acc[i] += __shfl_xor(acc[i], 16, 64);
        acc[i] += __shfl_xor(acc[i], 32, 64);
    }
    zacc += __shfl_xor(zacc, 16, 64);
    zacc += __shfl_xor(zacc, 32, 64);

    const float inv = 1.f / zacc;                    // z of head lh>>1
    float r[8];
#pragma unroll
    for (int i = 0; i < 8; i++) r[i] = acc[i] * inv;
    // mean over heads: head index = l bits 1..3
#pragma unroll
    for (int i = 0; i < 8; i++) {
        r[i] += __shfl_xor(r[i], 2, 64);
        r[i] += __shfl_xor(r[i], 4, 64);
        r[i] += __shfl_xor(r[i], 8, 64);
    }
    if (l < 2) {
        float4* op = (float4*)(out + (size_t)n * OD + l * 8);
        op[0] = make_float4(r[0] * 0.125f, r[1] * 0.125f, r[2] * 0.125f, r[3] * 0.125f);
        op[1] = make_float4(r[4] * 0.125f, r[5] * 0.125f, r[6] * 0.125f, r[7] * 0.125f);
    }
}

// ---------------- launch ------------------------------------------------------
extern "C" void kernel_launch(void* const* d_in, const int* in_sizes, int n_in,
                              void* d_out, int out_size, void* d_ws, size_t ws_size,
                              hipStream_t stream)
{
    const float* h  = (const float*)d_in[0];
    const float* Qw = (const float*)d_in[1];
    const float* Qb = (const float*)d_in[2];
    const float* Kw = (const float*)d_in[3];
    const float* Kb = (const float*)d_in[4];
    const float* Vw = (const float*)d_in[5];
    const float* Vb = (const float*)d_in[6];
    const int*   src = (const int*)d_in[7];
    const int*   dst = (const int*)d_in[8];

    char* ws = (char*)d_ws;
    _Float16* W16   = (_Float16*)ws;                   ws += (size_t)NOUT * IND * 2;
    float*    b_all = (float*)ws;                      ws += 288 * 4;
    __half*   KVbuf = (__half*)ws;                     ws += (size_t)NNODES * 256 * 2;
    _Float16* Qs16  = (_Float16*)ws;                   ws += (size_t)NNODES * OD * 2;
    int*      offs   = (int*)ws;                       ws += (size_t)NNODES * 4;
    int*      count  = (int*)ws;                       ws += (size_t)NNODES * 4;
    int*      bcount = (int*)ws;                       ws += 1024 * 4;
    unsigned int*   ebuck  = (unsigned int*)ws;        ws += (size_t)NBUCK * BCAP * 4;
    unsigned short* eidx16 = (unsigned short*)ws;      ws += (size_t)NBUCK * BCAP * 2;

    hipMemsetAsync(bcount, 0, 1024 * 4, stream);

    ka_scatter_w16<<<P1B + 1, 256, 0, stream>>>(
        src, dst, bcount, ebuck, Qw, Qb, Kw, Kb, Vw, Vb, W16, b_all);

    kb_proj_group<<<PB2 + NBUCK, 256, 0, stream>>>(
        h, W16, b_all, KVbuf, Qs16, ebuck, bcount, offs, count, eidx16);

    kc_gather<<<(NNODES + 3) / 4, 256, 0, stream>>>(
        (const uint4*)KVbuf, (const uint4*)Qs16, offs, count, eidx16, (float*)d_out);
}